// Round 14
// baseline (940.178 us; speedup 1.0000x reference)
//
#include <hip/hip_runtime.h>
#include <stdint.h>

typedef unsigned int u32;
typedef unsigned long long u64;

#define NN 32768
#define NE 262144
#define NC 128

// output element offsets (ALL FLOAT32)
#define O0 0u               // new_x [NN*128]
#define O1 4194304u         // cluster [NN]
#define O2 4227072u         // new_batch [NN]
#define O3 4259840u         // new_edge_score [NN]
#define O4 4292608u         // num_clusters [1]
#define O5 4292609u         // new_ei [2*NE]
#define O6 4816897u         // edge_valid [NE]
#define O7 5079041u         // e [NE]

#define HCAP (1u<<19)
#define NFULL 8
#define CNT0 8
#define MCAP 16384
#define SCAP 32768
#define SNB 32
#define MAXK 0xFFFFFFFFFFFFFFFFull
#define EMASK 0x3FFFFu

// ---------------- init: prep (block 0) + all per-call state ----------------
__global__ void ep_init(const float* Wt, const float* Ws, const float* bt, const float* bs,
                        double* u, double* c0, u32* counters,
                        u64* b0, u64* b1, u32* avail, int* cl,
                        u32* tkey, u32* tmin, unsigned char* premat) {
    u32 i = blockIdx.x*blockDim.x + threadIdx.x; // 512*256 = 131072
    if (blockIdx.x == 0 && threadIdx.x < 128) {
        int r = threadIdx.x;
        double s = 0.0;
        for (int j = 0; j < NC; j++) s += (double)Wt[r*NC+j] * (double)Ws[j];
        u[r] = s;
        if (r == 0) {
            double c = 0.0;
            for (int j = 0; j < NC; j++) c += (double)bt[j] * (double)Ws[j];
            *c0 = c + (double)bs[0];
        }
    }
    if (i < 64) counters[i] = 0u;
    if (i < NN) { b0[i] = MAXK; b1[i] = MAXK; cl[i] = -1; }
    if (i < NN/32) avail[i] = 0xFFFFFFFFu;
    ((unsigned short*)premat)[i] = 0;
    for (u32 j = i; j < HCAP; j += 131072u) { tkey[j] = 0xFFFFFFFFu; tmin[j] = 0xFFFFFFFFu; }
}

// ---------------- per-node f64 dot y[v] = x[v,:]·u ----------------
__global__ void ep_ynode(const float* x, const double* u, double* y) {
    int gid = blockIdx.x*blockDim.x + threadIdx.x;
    int v = gid >> 6, lane = threadIdx.x & 63;
    if (v >= NN) return;
    double t = (double)x[v*NC+lane]*u[lane] + (double)x[v*NC+lane+64]*u[lane+64];
    for (int off = 32; off; off >>= 1) t += __shfl_down(t, off, 64);
    if (lane == 0) y[v] = t;
}

// ---------------- per-edge score + unique priority + frontier push ----------------
__global__ void ep_escore(const int* src, const int* dst, const float* rnd, const double* y,
                          const double* c0, u64* fkey, u32* counters, float* out) {
    int e = blockIdx.x*blockDim.x + threadIdx.x;
    if (e >= NE) return;
    int s = src[e], d = dst[e];
    double z = y[s] + y[d] + *c0;
    double sc = 1.0/(1.0 + exp(-z));
    out[O7 + e] = (float)sc;
    u64 b = (u64)__double_as_longlong(z);
    u64 ord = (b & 0x8000000000000000ull) ? ~b : (b | 0x8000000000000000ull); // ascending z
    u64 P = ((~ord) & 0xFFFFFFFFFFFC0000ull) | (u64)(u32)e; // 46b score desc | 18b idx (unique)
    if ((double)rnd[e] <= sc) {
        u32 p = atomicAdd(&counters[CNT0], 1u);
        fkey[p] = P;
    }
}

// ---------------- full-grid priority-matching rounds (R6-exact, 2-buffer ping-pong) -
__device__ __forceinline__ bool ep_bit(const u32* a, u32 v) { return (a[v>>5] >> (v&31)) & 1u; }

__global__ void ep_rA(const u64* fkey, const int* src, const int* dst,
                      const u32* cnt, u64* bt, const u32* avail) {
    u32 n = *cnt;
    for (u32 i = blockIdx.x*blockDim.x + threadIdx.x; i < n; i += 65536u) {
        u64 P = fkey[i];
        u32 e = (u32)(P & EMASK);
        u32 s = (u32)src[e], d = (u32)dst[e];
        if (ep_bit(avail, s) && ep_bit(avail, d)) {
            atomicMin(&bt[s], P); atomicMin(&bt[d], P);
        }
    }
}

__global__ void ep_rB(const u64* fkey, const int* src, const int* dst,
                      const u32* cnt, u32* cntN, u64* fkeyN,
                      const u64* bt, u64* btN, u32* avail,
                      u64* mkey, unsigned char* premat, u32* counters) {
    u32 n = *cnt;
    for (u32 i = blockIdx.x*blockDim.x + threadIdx.x; i < n; i += 65536u) {
        u64 P = fkey[i];
        u32 e = (u32)(P & EMASK);
        u32 s = (u32)src[e], d = (u32)dst[e];
        if (!ep_bit(avail, s) || !ep_bit(avail, d)) continue; // dead
        if (bt[s] == P && bt[d] == P) {
            u32 slot = atomicAdd(&counters[2], 1u);
            mkey[slot] = P;
            premat[e] = 1;
            atomicAnd(&avail[s>>5], ~(1u<<(s&31)));
            atomicAnd(&avail[d>>5], ~(1u<<(d&31)));
        } else {
            u32 p = atomicAdd(cntN, 1u);
            fkeyN[p] = P;
            btN[s] = MAXK; btN[d] = MAXK;  // pre-reset next round's buffer
        }
    }
}

// ---------------- merge matched + remaining into one padded key list ----------------
__global__ void ep_merge(const u64* mk, const u64* fk, u32* counters, u64* ck) {
    u32 i = blockIdx.x*blockDim.x + threadIdx.x; // SNB*1024 threads
    u32 nm0 = counters[2];
    u32 cr  = counters[CNT0+NFULL];
    if (i == 0) { u32 tot = nm0 + cr; counters[4] = tot > SCAP ? SCAP : tot; }
    u64 K = MAXK;
    if (i < nm0) K = mk[i];
    else if (i < nm0 + cr && i < SCAP) K = fk[i-nm0];
    ck[i] = K;
}

// ---------------- fused 6-pass radix sort: 32 co-resident blocks + grid barrier -----
__device__ __forceinline__ u64 ep_peers(u32 d, bool real) {
    u64 m = ~0ull;
    #pragma unroll
    for (int b = 0; b < 8; b++) {
        u64 bb = __ballot((d >> b) & 1u);
        m &= ((d >> b) & 1u) ? bb : ~bb;
    }
    return m & __ballot(real);
}

__device__ __forceinline__ void ms_gbar(u32* bar) {
    __syncthreads();
    if (threadIdx.x == 0) {
        __threadfence();
        u32 gen = atomicAdd(&bar[1], 0u);
        if (atomicAdd(&bar[0], 1u) == SNB - 1) {
            atomicExch(&bar[0], 0u);
            __threadfence();
            atomicAdd(&bar[1], 1u);
        } else {
            while (atomicAdd(&bar[1], 0u) == gen) __builtin_amdgcn_s_sleep(8);
        }
        __threadfence();
    }
    __syncthreads();
}

__global__ void __launch_bounds__(64) ms_sort(u64* a, u64* b, u32* hist,
                                              const u32* counters, u32* bar) {
    __shared__ u32 h[256];
    int t = threadIdx.x; // 64 threads = 1 wave
    u32 blk = blockIdx.x;
    u32 total = counters[4];
    u64 *ki = a, *ko = b;
    for (int p = 0; p < 6; p++) {
        int shift = 16 + p*8;
        // ---- hist (single wave; LDS ops wave-ordered) ----
        h[t] = 0; h[t+64] = 0; h[t+128] = 0; h[t+192] = 0;
        for (int j = 0; j < 16; j++) {
            u32 idx = blk*1024u + (u32)j*64u + (u32)t;
            bool real = idx < total;
            u64 k = real ? ki[idx] : MAXK;
            u32 d = (u32)(k >> shift) & 255u;
            u64 m = ep_peers(d, real);
            if (real && t == (__ffsll((unsigned long long)m) - 1)) h[d] += (u32)__popcll(m);
        }
        hist[(u32)t*SNB + blk]       = h[t];
        hist[((u32)t+64)*SNB + blk]  = h[t+64];
        hist[((u32)t+128)*SNB + blk] = h[t+128];
        hist[((u32)t+192)*SNB + blk] = h[t+192];
        ms_gbar(bar);
        // ---- scan (block 0 only; 8192 entries, 128/thread) ----
        if (blk == 0) {
            int b2 = t*128;
            u32 s = 0;
            for (int j = 0; j < 128; j++) s += hist[b2+j];
            u32 x = s;
            for (int off = 1; off < 64; off <<= 1) { u32 yv = __shfl_up(x, off, 64); if (t >= off) x += yv; }
            u32 run = x - s;
            for (int j = 0; j < 128; j++) { u32 tmp = hist[b2+j]; hist[b2+j] = run; run += tmp; }
        }
        ms_gbar(bar);
        // ---- scatter (ballot rank, leader-updated counters) ----
        h[t] = 0; h[t+64] = 0; h[t+128] = 0; h[t+192] = 0;
        for (int j = 0; j < 16; j++) {
            u32 idx = blk*1024u + (u32)j*64u + (u32)t;
            bool real = idx < total;
            u64 k = real ? ki[idx] : MAXK;
            u32 d = (u32)(k >> shift) & 255u;
            u64 m = ep_peers(d, real);
            if (real) {
                u32 rank = (u32)__popcll(m & (((u64)1 << t) - 1ull));
                int leader = __ffsll((unsigned long long)m) - 1;
                u32 base = 0;
                if (t == leader) { base = h[d]; h[d] = base + (u32)__popcll(m); }
                base = __shfl(base, leader, 64);
                ko[hist[d*SNB + blk] + base + rank] = k;
            }
        }
        ms_gbar(bar);
        u64* tp = ki; ki = ko; ko = tp;
    }
}

// ---------------- mega-walk: compact + tag-claim match + emit + singleton scan ------
__global__ void __launch_bounds__(1024) ep_walk(const u64* sk, const int* src, const int* dst,
                                                const unsigned char* premat, u32* counters,
                                                const u32* availG, u32* mflag, u32* candIdx,
                                                u64* Mlist, int* cl, u32* slist,
                                                const int* batch, float* out) {
    __shared__ u32 avail[1024];       // 32768 bits
    __shared__ u32 claim[16384];      // claim arbiter (node & 16383)
    __shared__ u32 wsc[16];
    int t = threadIdx.x;
    avail[t] = availG[t];
    for (int j = t; j < 16384; j += 1024) claim[j] = 0xFFFFFFFFu;
    u32 total = counters[4];
    int b32 = t*32;

    // ---- phase 1: candidate compaction (thread owns entries [t*32, t*32+32)) ----
    u32 premask = 0, havemask = 0, cc = 0;
    for (int j = 0; j < 32; j++) {
        u32 i = (u32)(b32 + j);
        u32 have = (i < total) ? 1u : 0u;
        u32 pre = 0;
        if (have) pre = premat[(u32)(sk[i] & EMASK)] ? 1u : 0u;
        mflag[i] = pre;
        premask |= pre << j;
        havemask |= have << j;
        cc += have & ~pre & 1u;
    }
    __syncthreads();
    u32 x = cc;
    for (int off = 1; off < 64; off <<= 1) { u32 y = __shfl_up(x, off, 64); if ((t&63) >= off) x += y; }
    if ((t&63) == 63) wsc[t>>6] = x;
    __syncthreads();
    if (t < 16) {
        u32 ww = wsc[t];
        for (int off = 1; off < 16; off <<= 1) { u32 y = __shfl_up(ww, off, 16); if (t >= off) ww += y; }
        wsc[t] = ww;
    }
    __syncthreads();
    u32 cbase = ((t>>6) ? wsc[(t>>6)-1] : 0u) + x - cc;
    u32 ncand = wsc[15];
    for (int j = 0; j < 32; j++) {
        if (((havemask>>j)&1u) && !((premask>>j)&1u)) candIdx[cbase++] = (u32)(b32+j);
    }
    __threadfence_block();
    __syncthreads();

    // ---- phase 2: tag-claim matching over windows of 1024 (R12-proven) ----
    u32 iterTag = 0x3FFFFFu;
    for (u32 base = 0; base < ncand; base += 1024) {
        u32 j = base + (u32)t;
        bool have = j < ncand;
        u32 i = 0, s = 0, d = 0;
        if (have) {
            i = candIdx[j];
            u32 e = (u32)(sk[i] & EMASK);
            s = (u32)src[e]; d = (u32)dst[e];
        }
        u32 hs = s & 16383u, hd = d & 16383u;
        int st = 1; // 0 candidate, 1 dead, 2 matched
        if (have && ((avail[s>>5]>>(s&31))&1u) && ((avail[d>>5]>>(d&31))&1u)) st = 0;
        for (int guard = 0; guard < 4096; guard++) {
            u32 tag = (iterTag << 10) | (u32)t; // strictly decreasing tags
            if (st == 0) { atomicMin(&claim[hs], tag); atomicMin(&claim[hd], tag); }
            __syncthreads();
            if (st == 0) {
                bool aok = ((avail[s>>5]>>(s&31))&1u) && ((avail[d>>5]>>(d&31))&1u);
                if (!aok) st = 1;
                else if (claim[hs] == tag && claim[hd] == tag) {
                    st = 2;
                    atomicAnd(&avail[s>>5], ~(1u<<(s&31)));
                    atomicAnd(&avail[d>>5], ~(1u<<(d&31)));
                    mflag[i] = 1u;
                }
            }
            iterTag--;
            if (__syncthreads_count(st == 0) == 0) break;
        }
    }
    __threadfence_block();
    __syncthreads();

    // ---- phase 3: emit matched in sorted order (cid = prefix over mflag) ----
    u32 mc = 0, mmask = 0;
    for (int j = 0; j < 32; j++) {
        u32 f = mflag[b32+j] & 1u;
        mmask |= f << j;
        mc += f;
    }
    __syncthreads();
    x = mc;
    for (int off = 1; off < 64; off <<= 1) { u32 y = __shfl_up(x, off, 64); if ((t&63) >= off) x += y; }
    if ((t&63) == 63) wsc[t>>6] = x;
    __syncthreads();
    if (t < 16) {
        u32 ww = wsc[t];
        for (int off = 1; off < 16; off <<= 1) { u32 y = __shfl_up(ww, off, 16); if (t >= off) ww += y; }
        wsc[t] = ww;
    }
    __syncthreads();
    u32 mbase = ((t>>6) ? wsc[(t>>6)-1] : 0u) + x - mc;
    u32 nm = wsc[15];
    if (t == 0) counters[2] = nm;
    for (int j = 0; j < 32; j++) {
        if ((mmask>>j)&1u) {
            u32 i = (u32)(b32+j);
            u32 e = (u32)(sk[i] & EMASK);
            u32 s = (u32)src[e], d = (u32)dst[e];
            Mlist[mbase] = ((u64)e << 30) | ((u64)s << 15) | (u64)d;
            cl[s] = (int)mbase; cl[d] = (int)mbase;
            u32 mx = s > d ? s : d; // last-writer-wins = max node index
            out[O2 + mbase] = (float)batch[mx];
            out[O3 + mbase] = out[O7 + e];
            mbase++;
        }
    }
    __threadfence_block();
    __syncthreads();

    // ---- phase 4: singleton cid assignment (scanN fold; thread owns 32 nodes) ----
    u32 sc2 = 0;
    for (int j = 0; j < 32; j++) sc2 += (cl[b32+j] < 0) ? 1u : 0u;
    __syncthreads();
    x = sc2;
    for (int off = 1; off < 64; off <<= 1) { u32 y = __shfl_up(x, off, 64); if ((t&63) >= off) x += y; }
    if ((t&63) == 63) wsc[t>>6] = x;
    __syncthreads();
    if (t < 16) {
        u32 ww = wsc[t];
        for (int off = 1; off < 16; off <<= 1) { u32 y = __shfl_up(ww, off, 16); if (t >= off) ww += y; }
        wsc[t] = ww;
    }
    __syncthreads();
    u32 excl = ((t>>6) ? wsc[(t>>6)-1] : 0u) + x - sc2;
    u32 stotal = wsc[15];
    if (t == 0) {
        counters[3] = nm + stotal;
        counters[6] = stotal;
        out[O4] = (float)(nm + stotal);
    }
    u32 run = nm + excl;
    for (int j = 0; j < 32; j++) {
        if (cl[b32+j] < 0) {
            slist[run - nm] = (u32)(b32 + j);
            cl[b32+j] = (int)(run++);
        }
    }
}

// ---------------- cluster ids + O2/O3 tails ----------------
__global__ void ep_out_nodes(const int* cl, const int* batch, const u32* counters, float* out) {
    int v = blockIdx.x*blockDim.x + threadIdx.x;
    if (v >= NN) return;
    u32 nm = counters[2], ncl = counters[3];
    int c = cl[v];
    out[O1 + v] = (float)c;
    if (c >= (int)nm) out[O2 + c] = (float)batch[v]; // singleton batch
    if (v >= (int)nm) out[O3 + v] = 1.0f;            // default edge score
    if (v >= (int)ncl) out[O2 + v] = 0.0f;           // batch tail zeros
}

// ---------------- new_x matched rows ----------------
__global__ void ep_newx_m(const float* x, const float* Wt, const float* bt,
                          const u64* Mlist, const u32* counters, float* out) {
    __shared__ u64 ml[32];
    __shared__ float m[32][128];
    u32 nm = counters[2];
    u32 base = blockIdx.x * 32u;
    if (base >= nm) return;
    int t = threadIdx.x, lane = t & 63, wv = t >> 6;
    if (t < 32) { u32 r = base + (u32)t; ml[t] = (r < nm) ? Mlist[r] : 0ull; }
    __syncthreads();
    for (int i = t; i < 4096; i += 256) {
        int r = i >> 7, k = i & 127;
        u64 v = ml[r];
        u32 s = (u32)((v>>15)&0x7FFF), d = (u32)(v&0x7FFF);
        m[r][k] = x[s*NC+k] + x[d*NC+k];
    }
    __syncthreads();
    float a0[8], a1[8];
    #pragma unroll
    for (int r = 0; r < 8; r++) { a0[r] = bt[lane]; a1[r] = bt[lane+64]; }
    for (int k = 0; k < 128; k++) {
        float w0 = Wt[k*NC+lane], w1 = Wt[k*NC+lane+64];
        #pragma unroll
        for (int r = 0; r < 8; r++) { float mm = m[wv*8+r][k]; a0[r] += mm*w0; a1[r] += mm*w1; }
    }
    #pragma unroll
    for (int r = 0; r < 8; r++) {
        u32 row = base + (u32)(wv*8 + r);
        if (row < nm) {
            out[O0 + (size_t)row*NC + lane]      = a0[r];
            out[O0 + (size_t)row*NC + lane + 64] = a1[r];
        }
    }
}

// ---------------- new_x singleton rows + zero tail ----------------
__global__ void ep_newx_s(const float* x, const float* Wt, const float* bt,
                          const u32* slist, const u32* counters, float* out) {
    __shared__ u32 nodes[32];
    __shared__ float m[32][128];
    u32 nm = counters[2], ncl = counters[3], sc = counters[6];
    u32 base = nm + blockIdx.x * 32u; // grid 1024 blocks covers rows [nm, nm+32768)
    if (base >= NN) return;
    int t = threadIdx.x, lane = t & 63, wv = t >> 6;
    if (base >= ncl) { // pure zero rows
        for (int i = t; i < 4096; i += 256) {
            u32 row = base + (u32)(i >> 7);
            if (row < NN) out[O0 + (size_t)row*NC + (i & 127)] = 0.0f;
        }
        return;
    }
    if (t < 32) { u32 p = base - nm + (u32)t; nodes[t] = (p < sc) ? slist[p] : slist[0]; }
    __syncthreads();
    for (int i = t; i < 4096; i += 256) {
        int r = i >> 7, k = i & 127;
        m[r][k] = 2.0f * x[nodes[r]*NC + k];
    }
    __syncthreads();
    float a0[8], a1[8];
    #pragma unroll
    for (int r = 0; r < 8; r++) { a0[r] = bt[lane]; a1[r] = bt[lane+64]; }
    for (int k = 0; k < 128; k++) {
        float w0 = Wt[k*NC+lane], w1 = Wt[k*NC+lane+64];
        #pragma unroll
        for (int r = 0; r < 8; r++) { float mm = m[wv*8+r][k]; a0[r] += mm*w0; a1[r] += mm*w1; }
    }
    #pragma unroll
    for (int r = 0; r < 8; r++) {
        u32 row = base + (u32)(wv*8 + r);
        if (row >= NN) continue;
        if (row < ncl) {
            out[O0 + (size_t)row*NC + lane]      = a0[r];
            out[O0 + (size_t)row*NC + lane + 64] = a1[r];
        } else {
            out[O0 + (size_t)row*NC + lane]      = 0.0f;
            out[O0 + (size_t)row*NC + lane + 64] = 0.0f;
        }
    }
}

// ---------------- new_ei + edge_valid via min-index hash ----------------
__global__ void ep_newei(const int* src, const int* dst, const int* cl,
                         u32* tkey, u32* tmin, u32* eslot, float* out) {
    int e = blockIdx.x*blockDim.x + threadIdx.x;
    if (e >= NE) return;
    u32 cs = (u32)cl[src[e]], cd = (u32)cl[dst[e]];
    out[O5 + e]      = (float)cs;
    out[O5 + NE + e] = (float)cd;
    u32 key = (cs << 15) | cd;
    u32 slot = ((key * 2654435761u) >> 11) & (HCAP-1);
    while (true) {
        u32 k = tkey[slot];
        if (k == key) break;
        if (k == 0xFFFFFFFFu) {
            u32 old = atomicCAS(&tkey[slot], 0xFFFFFFFFu, key);
            if (old == 0xFFFFFFFFu || old == key) break;
        }
        slot = (slot + 1) & (HCAP-1);
    }
    eslot[e] = slot | ((cs != cd) ? 0x80000000u : 0u);
    atomicMin(&tmin[slot], (u32)e);
}

__global__ void ep_valid(const u32* tmin, const u32* eslot, float* out) {
    int e = blockIdx.x*blockDim.x + threadIdx.x;
    if (e >= NE) return;
    u32 sl = eslot[e];
    bool valid = (tmin[sl & 0x7FFFFFFFu] == (u32)e) && (sl >> 31);
    out[O6 + e] = valid ? 1.0f : 0.0f;
}

// =============================== host ===============================
extern "C" void kernel_launch(void* const* d_in, const int* in_sizes, int n_in,
                              void* d_out, int out_size, void* d_ws, size_t ws_size,
                              hipStream_t stream) {
    (void)in_sizes; (void)n_in; (void)out_size; (void)ws_size;
    const float* x    = (const float*)d_in[0];
    const int*   ei   = (const int*)d_in[1];
    const int*   src  = ei;
    const int*   dst  = ei + NE;
    const int*   batch= (const int*)d_in[2];
    const float* rnd  = (const float*)d_in[3];
    const float* Wt   = (const float*)d_in[4];
    const float* bt   = (const float*)d_in[5];
    const float* Ws   = (const float*)d_in[6];
    const float* bs   = (const float*)d_in[7];
    float* out = (float*)d_out;

    char* w = (char*)d_ws;
    double* u  = (double*)w;
    double* c0 = (double*)(w + 1024);
    u32* counters = (u32*)(w + 2048);
    size_t off = 4096;
    double* y   = (double*)(w + off); off += (size_t)NN*8;
    u64* fkeyA  = (u64*)(w + off); off += (size_t)NE*8;
    u64* fkeyB  = (u64*)(w + off); off += (size_t)NE*8;
    u64* mkeyA  = (u64*)(w + off); off += (size_t)MCAP*8;
    u64* combK  = (u64*)(w + off); off += (size_t)SCAP*8;
    u64* combK2 = (u64*)(w + off); off += (size_t)SCAP*8;
    u64* bt0    = (u64*)(w + off); off += (size_t)NN*8;
    u64* bt1    = (u64*)(w + off); off += (size_t)NN*8;
    u32* avail  = (u32*)(w + off); off += NN/8;
    int* cl     = (int*)(w + off); off += (size_t)NN*4;
    u64* Mlist  = (u64*)(w + off); off += (size_t)NN*8;
    u32* hist   = (u32*)(w + off); off += 8192*4;
    u32* mflag  = (u32*)(w + off); off += (size_t)SCAP*4;
    u32* candIdx= (u32*)(w + off); off += (size_t)SCAP*4;
    u32* slist  = (u32*)(w + off); off += (size_t)NN*4;
    unsigned char* premat = (unsigned char*)(w + off); off += NE;
    u32* tkey   = (u32*)(w + off); off += (size_t)HCAP*4;
    u32* tmin   = (u32*)(w + off); off += (size_t)HCAP*4;
    u32* eslot  = (u32*)(w + off); off += (size_t)NE*4;

    ep_init<<<512, 256, 0, stream>>>(Wt, Ws, bt, bs, u, c0, counters,
                                     bt0, bt1, avail, cl, tkey, tmin, premat);
    ep_ynode<<<8192, 256, 0, stream>>>(x, u, y);
    ep_escore<<<1024, 256, 0, stream>>>(src, dst, rnd, y, c0, fkeyA, counters, out);

    // NFULL rounds of (rA, rB) with 2-buffer ping-pong bestT (key-only records)
    u64 *fk = fkeyA, *fk2 = fkeyB;
    u64 *bc = bt0, *bn = bt1;
    for (u32 rd = 0; rd < NFULL; rd++) {
        ep_rA<<<256, 256, 0, stream>>>(fk, src, dst, &counters[CNT0+rd], bc, avail);
        ep_rB<<<256, 256, 0, stream>>>(fk, src, dst, &counters[CNT0+rd], &counters[CNT0+rd+1],
                                       fk2, bc, bn, avail, mkeyA, premat, counters);
        u64* tp;
        tp = fk; fk = fk2; fk2 = tp;
        tp = bc; bc = bn; bn = tp;
    }

    ep_merge<<<SNB, 1024, 0, stream>>>(mkeyA, fk, counters, combK);
    // fused 6-pass sort (even # of passes -> sorted keys land back in combK)
    ms_sort<<<SNB, 64, 0, stream>>>(combK, combK2, hist, counters, &counters[32]);

    // mega-walk: compact + match + emit + singleton scan
    ep_walk<<<1, 1024, 0, stream>>>(combK, src, dst, premat, counters, avail,
                                    mflag, candIdx, Mlist, cl, slist, batch, out);

    ep_out_nodes<<<128, 256, 0, stream>>>(cl, batch, counters, out);

    ep_newx_m<<<512, 256, 0, stream>>>(x, Wt, bt, Mlist, counters, out);
    ep_newx_s<<<1024, 256, 0, stream>>>(x, Wt, bt, slist, counters, out);

    ep_newei<<<1024, 256, 0, stream>>>(src, dst, cl, tkey, tmin, eslot, out);
    ep_valid<<<1024, 256, 0, stream>>>(tmin, eslot, out);
}

// Round 15
// 772.911 us; speedup vs baseline: 1.2164x; 1.2164x over previous
//
#include <hip/hip_runtime.h>
#include <stdint.h>

typedef unsigned int u32;
typedef unsigned long long u64;

#define NN 32768
#define NE 262144
#define NC 128

// output element offsets (ALL FLOAT32)
#define O0 0u               // new_x [NN*128]
#define O1 4194304u         // cluster [NN]
#define O2 4227072u         // new_batch [NN]
#define O3 4259840u         // new_edge_score [NN]
#define O4 4292608u         // num_clusters [1]
#define O5 4292609u         // new_ei [2*NE]
#define O6 4816897u         // edge_valid [NE]
#define O7 5079041u         // e [NE]

#define HCAP (1u<<19)
#define NFULL 8
#define CNT0 8
#define MCAP 16384
#define SCAP 32768
#define SNB 32
#define MAXK 0xFFFFFFFFFFFFFFFFull
#define EMASK 0x3FFFFu

// ---------------- init: prep (block 0) + all per-call state ----------------
__global__ void ep_init(const float* Wt, const float* Ws, const float* bt, const float* bs,
                        double* u, double* c0, u32* counters,
                        u64* b0, u64* b1, u32* avail, int* cl,
                        u32* tkey, u32* tmin, unsigned char* premat, u32* mflag) {
    u32 i = blockIdx.x*blockDim.x + threadIdx.x; // 512*256 = 131072
    if (blockIdx.x == 0 && threadIdx.x < 128) {
        int r = threadIdx.x;
        double s = 0.0;
        for (int j = 0; j < NC; j++) s += (double)Wt[r*NC+j] * (double)Ws[j];
        u[r] = s;
        if (r == 0) {
            double c = 0.0;
            for (int j = 0; j < NC; j++) c += (double)bt[j] * (double)Ws[j];
            *c0 = c + (double)bs[0];
        }
    }
    if (i < 64) counters[i] = 0u;
    if (i < NN) { b0[i] = MAXK; b1[i] = MAXK; cl[i] = -1; }
    if (i < NN/32) avail[i] = 0xFFFFFFFFu;
    if (i < SCAP) mflag[i] = 0u;
    ((unsigned short*)premat)[i] = 0;
    for (u32 j = i; j < HCAP; j += 131072u) { tkey[j] = 0xFFFFFFFFu; tmin[j] = 0xFFFFFFFFu; }
}

// ---------------- per-node f64 dot y[v] = x[v,:]·u ----------------
__global__ void ep_ynode(const float* x, const double* u, double* y) {
    int gid = blockIdx.x*blockDim.x + threadIdx.x;
    int v = gid >> 6, lane = threadIdx.x & 63;
    if (v >= NN) return;
    double t = (double)x[v*NC+lane]*u[lane] + (double)x[v*NC+lane+64]*u[lane+64];
    for (int off = 32; off; off >>= 1) t += __shfl_down(t, off, 64);
    if (lane == 0) y[v] = t;
}

// ---------------- per-edge score + unique priority + frontier push ----------------
__global__ void ep_escore(const int* src, const int* dst, const float* rnd, const double* y,
                          const double* c0, u64* fkey, u32* counters, float* out) {
    int e = blockIdx.x*blockDim.x + threadIdx.x;
    if (e >= NE) return;
    int s = src[e], d = dst[e];
    double z = y[s] + y[d] + *c0;
    double sc = 1.0/(1.0 + exp(-z));
    out[O7 + e] = (float)sc;
    u64 b = (u64)__double_as_longlong(z);
    u64 ord = (b & 0x8000000000000000ull) ? ~b : (b | 0x8000000000000000ull); // ascending z
    u64 P = ((~ord) & 0xFFFFFFFFFFFC0000ull) | (u64)(u32)e; // 46b score desc | 18b idx (unique)
    if ((double)rnd[e] <= sc) {
        u32 p = atomicAdd(&counters[CNT0], 1u);
        fkey[p] = P;
    }
}

// ---------------- full-grid priority-matching rounds (R6-exact, 2-buffer ping-pong) -
__device__ __forceinline__ bool ep_bit(const u32* a, u32 v) { return (a[v>>5] >> (v&31)) & 1u; }

__global__ void ep_rA(const u64* fkey, const int* src, const int* dst,
                      const u32* cnt, u64* bt, const u32* avail) {
    u32 n = *cnt;
    for (u32 i = blockIdx.x*blockDim.x + threadIdx.x; i < n; i += 65536u) {
        u64 P = fkey[i];
        u32 e = (u32)(P & EMASK);
        u32 s = (u32)src[e], d = (u32)dst[e];
        if (ep_bit(avail, s) && ep_bit(avail, d)) {
            atomicMin(&bt[s], P); atomicMin(&bt[d], P);
        }
    }
}

__global__ void ep_rB(const u64* fkey, const int* src, const int* dst,
                      const u32* cnt, u32* cntN, u64* fkeyN,
                      const u64* bt, u64* btN, u32* avail,
                      u64* mkey, unsigned char* premat, u32* counters) {
    u32 n = *cnt;
    for (u32 i = blockIdx.x*blockDim.x + threadIdx.x; i < n; i += 65536u) {
        u64 P = fkey[i];
        u32 e = (u32)(P & EMASK);
        u32 s = (u32)src[e], d = (u32)dst[e];
        if (!ep_bit(avail, s) || !ep_bit(avail, d)) continue; // dead
        if (bt[s] == P && bt[d] == P) {
            u32 slot = atomicAdd(&counters[2], 1u);
            mkey[slot] = P;
            premat[e] = 1;
            atomicAnd(&avail[s>>5], ~(1u<<(s&31)));
            atomicAnd(&avail[d>>5], ~(1u<<(d&31)));
        } else {
            u32 p = atomicAdd(cntN, 1u);
            fkeyN[p] = P;
            btN[s] = MAXK; btN[d] = MAXK;  // pre-reset next round's buffer
        }
    }
}

// ---------------- merge matched + remaining into one padded key list ----------------
__global__ void ep_merge(const u64* mk, const u64* fk, u32* counters, u64* ck) {
    u32 i = blockIdx.x*blockDim.x + threadIdx.x; // SNB*1024 threads
    u32 nm0 = counters[2];
    u32 cr  = counters[CNT0+NFULL];
    if (i == 0) { u32 tot = nm0 + cr; counters[4] = tot > SCAP ? SCAP : tot; }
    u64 K = MAXK;
    if (i < nm0) K = mk[i];
    else if (i < nm0 + cr && i < SCAP) K = fk[i-nm0];
    ck[i] = K;
}

// ---------------- fused 6-pass radix sort: 32 co-resident blocks + grid barrier -----
__device__ __forceinline__ u64 ep_peers(u32 d, bool real) {
    u64 m = ~0ull;
    #pragma unroll
    for (int b = 0; b < 8; b++) {
        u64 bb = __ballot((d >> b) & 1u);
        m &= ((d >> b) & 1u) ? bb : ~bb;
    }
    return m & __ballot(real);
}

__device__ __forceinline__ void ms_gbar(u32* bar) {
    __syncthreads();
    if (threadIdx.x == 0) {
        __threadfence();
        u32 gen = atomicAdd(&bar[1], 0u);
        if (atomicAdd(&bar[0], 1u) == SNB - 1) {
            atomicExch(&bar[0], 0u);
            __threadfence();
            atomicAdd(&bar[1], 1u);
        } else {
            while (atomicAdd(&bar[1], 0u) == gen) __builtin_amdgcn_s_sleep(8);
        }
        __threadfence();
    }
    __syncthreads();
}

__global__ void __launch_bounds__(64) ms_sort(u64* a, u64* b, u32* hist,
                                              const u32* counters, u32* bar) {
    __shared__ u32 h[256];
    int t = threadIdx.x; // 64 threads = 1 wave
    u32 blk = blockIdx.x;
    u32 total = counters[4];
    u64 *ki = a, *ko = b;
    for (int p = 0; p < 6; p++) {
        int shift = 16 + p*8;
        // ---- hist ----
        h[t] = 0; h[t+64] = 0; h[t+128] = 0; h[t+192] = 0;
        for (int j = 0; j < 16; j++) {
            u32 idx = blk*1024u + (u32)j*64u + (u32)t;
            bool real = idx < total;
            u64 k = real ? ki[idx] : MAXK;
            u32 d = (u32)(k >> shift) & 255u;
            u64 m = ep_peers(d, real);
            if (real && t == (__ffsll((unsigned long long)m) - 1)) h[d] += (u32)__popcll(m);
        }
        hist[(u32)t*SNB + blk]       = h[t];
        hist[((u32)t+64)*SNB + blk]  = h[t+64];
        hist[((u32)t+128)*SNB + blk] = h[t+128];
        hist[((u32)t+192)*SNB + blk] = h[t+192];
        ms_gbar(bar);
        // ---- scan (block 0 only) ----
        if (blk == 0) {
            int b2 = t*128;
            u32 s = 0;
            for (int j = 0; j < 128; j++) s += hist[b2+j];
            u32 x = s;
            for (int off = 1; off < 64; off <<= 1) { u32 yv = __shfl_up(x, off, 64); if (t >= off) x += yv; }
            u32 run = x - s;
            for (int j = 0; j < 128; j++) { u32 tmp = hist[b2+j]; hist[b2+j] = run; run += tmp; }
        }
        ms_gbar(bar);
        // ---- scatter ----
        h[t] = 0; h[t+64] = 0; h[t+128] = 0; h[t+192] = 0;
        for (int j = 0; j < 16; j++) {
            u32 idx = blk*1024u + (u32)j*64u + (u32)t;
            bool real = idx < total;
            u64 k = real ? ki[idx] : MAXK;
            u32 d = (u32)(k >> shift) & 255u;
            u64 m = ep_peers(d, real);
            if (real) {
                u32 rank = (u32)__popcll(m & (((u64)1 << t) - 1ull));
                int leader = __ffsll((unsigned long long)m) - 1;
                u32 base = 0;
                if (t == leader) { base = h[d]; h[d] = base + (u32)__popcll(m); }
                base = __shfl(base, leader, 64);
                ko[hist[d*SNB + blk] + base + rank] = k;
            }
        }
        ms_gbar(bar);
        u64* tp = ki; ki = ko; ko = tp;
    }
}

// ---------------- barriered walk over sorted list (tag claims) + fused msum ---------
__global__ void __launch_bounds__(1024) ep_walk(const u64* sk, const int* src, const int* dst,
                                                const unsigned char* premat, u32* counters,
                                                const u32* availG, u32* mflag, u32* msums) {
    __shared__ u32 avail[1024];       // 32768 bits
    __shared__ u32 claim[16384];      // claim arbiter (node & 16383)
    __shared__ u32 part[1024];
    __shared__ u32 segs[32];
    int t = threadIdx.x;
    avail[t] = availG[t];
    for (int j = t; j < 16384; j += 1024) claim[j] = 0xFFFFFFFFu;
    __syncthreads();
    u32 total = counters[4];
    u32 iterTag = 0x3FFFFFu; // strictly decreasing across ALL iterations
    for (u32 base = 0; base < total; base += 1024) {
        u32 i = base + (u32)t;
        bool have = i < total;
        u32 s = 0, d = 0;
        int st = 1; // 0 candidate, 1 dead/pre, 2 matched
        if (have) {
            u32 e = (u32)(sk[i] & EMASK);
            if (premat[e]) {
                mflag[i] = 1u; // pre-matched: record, inert in claims
            } else {
                s = (u32)src[e]; d = (u32)dst[e];
                if (((avail[s>>5]>>(s&31))&1u) && ((avail[d>>5]>>(d&31))&1u)) st = 0;
            }
        }
        u32 hs = s & 16383u, hd = d & 16383u;
        for (int guard = 0; guard < 4096; guard++) {
            u32 tag = (iterTag << 10) | (u32)t;
            if (st == 0) { atomicMin(&claim[hs], tag); atomicMin(&claim[hd], tag); }
            __syncthreads();
            if (st == 0) {
                bool aok = ((avail[s>>5]>>(s&31))&1u) && ((avail[d>>5]>>(d&31))&1u);
                if (!aok) st = 1;
                else if (claim[hs] == tag && claim[hd] == tag) {
                    st = 2;
                    atomicAnd(&avail[s>>5], ~(1u<<(s&31)));
                    atomicAnd(&avail[d>>5], ~(1u<<(d&31)));
                    mflag[i] = 1u;
                }
            }
            iterTag--;
            if (__syncthreads_count(st == 0) == 0) break;
        }
    }
    __threadfence_block();
    __syncthreads();
    // fused msum + exclusive scan (32 segments of 1024 over mflag[32768])
    u32 p = 0; int b2 = t*32;
    for (int j = 0; j < 32; j++) p += mflag[b2+j];
    part[t] = p;
    __syncthreads();
    if (t < 32) { u32 sg = 0; for (int j = 0; j < 32; j++) sg += part[t*32+j]; segs[t] = sg; }
    __syncthreads();
    if (t == 0) { u32 a = 0; for (int g = 0; g < 32; g++) { msums[g] = a; a += segs[g]; } counters[2] = a; }
}

// ---------------- cid emit: parallel scan over match flags ----------------
__global__ void ep_memit(const u64* sk, const int* src, const int* dst,
                         const u32* mflag, const u32* msums,
                         const int* batch, u64* Mlist, int* cl, float* out) {
    __shared__ u32 w[16];
    int t = threadIdx.x;
    u32 i = blockIdx.x*1024 + t;
    u32 m = mflag[i];
    u32 x = m;
    for (int off = 1; off < 64; off <<= 1) { u32 y = __shfl_up(x, off, 64); if ((t&63) >= off) x += y; }
    if ((t&63) == 63) w[t>>6] = x;
    __syncthreads();
    if (t < 16) {
        u32 ww = w[t];
        for (int off = 1; off < 16; off <<= 1) { u32 y = __shfl_up(ww, off, 16); if (t >= off) ww += y; }
        w[t] = ww;
    }
    __syncthreads();
    u32 excl = ((t>>6) ? w[(t>>6)-1] : 0u) + x - m;
    if (m) {
        u32 cid = msums[blockIdx.x] + excl;
        u32 e = (u32)(sk[i] & EMASK);
        u32 s = (u32)src[e], d = (u32)dst[e];
        Mlist[cid] = ((u64)e << 30) | ((u64)s << 15) | (u64)d;
        cl[s] = (int)cid; cl[d] = (int)cid;
        u32 mx = s > d ? s : d; // last-writer-wins = max node index
        out[O2 + cid] = (float)batch[mx];
        out[O3 + cid] = out[O7 + e];
    }
}

// ---------------- singleton cid assignment + compacted singleton list ----------------
__global__ void ep_scanN(int* cl, u32* counters, u32* slist, float* out) {
    __shared__ u32 w[16];
    int t = threadIdx.x;
    int base = t*32;
    u32 s = 0;
    for (int j = 0; j < 32; j++) s += (cl[base+j] < 0) ? 1u : 0u;
    u32 x = s;
    for (int off = 1; off < 64; off <<= 1) { u32 y = __shfl_up(x, off, 64); if ((t&63) >= off) x += y; }
    if ((t&63) == 63) w[t>>6] = x;
    __syncthreads();
    if (t < 16) {
        u32 ww = w[t];
        for (int off = 1; off < 16; off <<= 1) { u32 y = __shfl_up(ww, off, 16); if (t >= off) ww += y; }
        w[t] = ww;
    }
    __syncthreads();
    u32 excl = ((t>>6) ? w[(t>>6)-1] : 0u) + x - s;
    u32 total = w[15];
    u32 nm = counters[2];
    if (t == 0) {
        counters[3] = nm + total;
        counters[6] = total;
        out[O4] = (float)(nm + total);
    }
    u32 run = nm + excl;
    for (int j = 0; j < 32; j++) {
        if (cl[base+j] < 0) {
            slist[run - nm] = (u32)(base + j);
            cl[base+j] = (int)(run++);
        }
    }
}

// ---------------- cluster ids + O2/O3 tails ----------------
__global__ void ep_out_nodes(const int* cl, const int* batch, const u32* counters, float* out) {
    int v = blockIdx.x*blockDim.x + threadIdx.x;
    if (v >= NN) return;
    u32 nm = counters[2], ncl = counters[3];
    int c = cl[v];
    out[O1 + v] = (float)c;
    if (c >= (int)nm) out[O2 + c] = (float)batch[v]; // singleton batch
    if (v >= (int)nm) out[O3 + v] = 1.0f;            // default edge score
    if (v >= (int)ncl) out[O2 + v] = 0.0f;           // batch tail zeros
}

// ---------------- new_x matched rows ----------------
__global__ void ep_newx_m(const float* x, const float* Wt, const float* bt,
                          const u64* Mlist, const u32* counters, float* out) {
    __shared__ u64 ml[32];
    __shared__ float m[32][128];
    u32 nm = counters[2];
    u32 base = blockIdx.x * 32u;
    if (base >= nm) return;
    int t = threadIdx.x, lane = t & 63, wv = t >> 6;
    if (t < 32) { u32 r = base + (u32)t; ml[t] = (r < nm) ? Mlist[r] : 0ull; }
    __syncthreads();
    for (int i = t; i < 4096; i += 256) {
        int r = i >> 7, k = i & 127;
        u64 v = ml[r];
        u32 s = (u32)((v>>15)&0x7FFF), d = (u32)(v&0x7FFF);
        m[r][k] = x[s*NC+k] + x[d*NC+k];
    }
    __syncthreads();
    float a0[8], a1[8];
    #pragma unroll
    for (int r = 0; r < 8; r++) { a0[r] = bt[lane]; a1[r] = bt[lane+64]; }
    for (int k = 0; k < 128; k++) {
        float w0 = Wt[k*NC+lane], w1 = Wt[k*NC+lane+64];
        #pragma unroll
        for (int r = 0; r < 8; r++) { float mm = m[wv*8+r][k]; a0[r] += mm*w0; a1[r] += mm*w1; }
    }
    #pragma unroll
    for (int r = 0; r < 8; r++) {
        u32 row = base + (u32)(wv*8 + r);
        if (row < nm) {
            out[O0 + (size_t)row*NC + lane]      = a0[r];
            out[O0 + (size_t)row*NC + lane + 64] = a1[r];
        }
    }
}

// ---------------- new_x singleton rows + zero tail ----------------
__global__ void ep_newx_s(const float* x, const float* Wt, const float* bt,
                          const u32* slist, const u32* counters, float* out) {
    __shared__ u32 nodes[32];
    __shared__ float m[32][128];
    u32 nm = counters[2], ncl = counters[3], sc = counters[6];
    u32 base = nm + blockIdx.x * 32u; // grid 1024 blocks covers rows [nm, nm+32768)
    if (base >= NN) return;
    int t = threadIdx.x, lane = t & 63, wv = t >> 6;
    if (base >= ncl) { // pure zero rows
        for (int i = t; i < 4096; i += 256) {
            u32 row = base + (u32)(i >> 7);
            if (row < NN) out[O0 + (size_t)row*NC + (i & 127)] = 0.0f;
        }
        return;
    }
    if (t < 32) { u32 p = base - nm + (u32)t; nodes[t] = (p < sc) ? slist[p] : slist[0]; }
    __syncthreads();
    for (int i = t; i < 4096; i += 256) {
        int r = i >> 7, k = i & 127;
        m[r][k] = 2.0f * x[nodes[r]*NC + k];
    }
    __syncthreads();
    float a0[8], a1[8];
    #pragma unroll
    for (int r = 0; r < 8; r++) { a0[r] = bt[lane]; a1[r] = bt[lane+64]; }
    for (int k = 0; k < 128; k++) {
        float w0 = Wt[k*NC+lane], w1 = Wt[k*NC+lane+64];
        #pragma unroll
        for (int r = 0; r < 8; r++) { float mm = m[wv*8+r][k]; a0[r] += mm*w0; a1[r] += mm*w1; }
    }
    #pragma unroll
    for (int r = 0; r < 8; r++) {
        u32 row = base + (u32)(wv*8 + r);
        if (row >= NN) continue;
        if (row < ncl) {
            out[O0 + (size_t)row*NC + lane]      = a0[r];
            out[O0 + (size_t)row*NC + lane + 64] = a1[r];
        } else {
            out[O0 + (size_t)row*NC + lane]      = 0.0f;
            out[O0 + (size_t)row*NC + lane + 64] = 0.0f;
        }
    }
}

// ---------------- new_ei + edge_valid via min-index hash ----------------
__global__ void ep_newei(const int* src, const int* dst, const int* cl,
                         u32* tkey, u32* tmin, u32* eslot, float* out) {
    int e = blockIdx.x*blockDim.x + threadIdx.x;
    if (e >= NE) return;
    u32 cs = (u32)cl[src[e]], cd = (u32)cl[dst[e]];
    out[O5 + e]      = (float)cs;
    out[O5 + NE + e] = (float)cd;
    u32 key = (cs << 15) | cd;
    u32 slot = ((key * 2654435761u) >> 11) & (HCAP-1);
    while (true) {
        u32 k = tkey[slot];
        if (k == key) break;
        if (k == 0xFFFFFFFFu) {
            u32 old = atomicCAS(&tkey[slot], 0xFFFFFFFFu, key);
            if (old == 0xFFFFFFFFu || old == key) break;
        }
        slot = (slot + 1) & (HCAP-1);
    }
    eslot[e] = slot | ((cs != cd) ? 0x80000000u : 0u);
    atomicMin(&tmin[slot], (u32)e);
}

__global__ void ep_valid(const u32* tmin, const u32* eslot, float* out) {
    int e = blockIdx.x*blockDim.x + threadIdx.x;
    if (e >= NE) return;
    u32 sl = eslot[e];
    bool valid = (tmin[sl & 0x7FFFFFFFu] == (u32)e) && (sl >> 31);
    out[O6 + e] = valid ? 1.0f : 0.0f;
}

// =============================== host ===============================
extern "C" void kernel_launch(void* const* d_in, const int* in_sizes, int n_in,
                              void* d_out, int out_size, void* d_ws, size_t ws_size,
                              hipStream_t stream) {
    (void)in_sizes; (void)n_in; (void)out_size; (void)ws_size;
    const float* x    = (const float*)d_in[0];
    const int*   ei   = (const int*)d_in[1];
    const int*   src  = ei;
    const int*   dst  = ei + NE;
    const int*   batch= (const int*)d_in[2];
    const float* rnd  = (const float*)d_in[3];
    const float* Wt   = (const float*)d_in[4];
    const float* bt   = (const float*)d_in[5];
    const float* Ws   = (const float*)d_in[6];
    const float* bs   = (const float*)d_in[7];
    float* out = (float*)d_out;

    char* w = (char*)d_ws;
    double* u  = (double*)w;
    double* c0 = (double*)(w + 1024);
    u32* counters = (u32*)(w + 2048);
    size_t off = 4096;
    double* y   = (double*)(w + off); off += (size_t)NN*8;
    u64* fkeyA  = (u64*)(w + off); off += (size_t)NE*8;
    u64* fkeyB  = (u64*)(w + off); off += (size_t)NE*8;
    u64* mkeyA  = (u64*)(w + off); off += (size_t)MCAP*8;
    u64* combK  = (u64*)(w + off); off += (size_t)SCAP*8;
    u64* combK2 = (u64*)(w + off); off += (size_t)SCAP*8;
    u64* bt0    = (u64*)(w + off); off += (size_t)NN*8;
    u64* bt1    = (u64*)(w + off); off += (size_t)NN*8;
    u32* avail  = (u32*)(w + off); off += NN/8;
    int* cl     = (int*)(w + off); off += (size_t)NN*4;
    u64* Mlist  = (u64*)(w + off); off += (size_t)NN*8;
    u32* hist   = (u32*)(w + off); off += 8192*4;
    u32* mflag  = (u32*)(w + off); off += (size_t)SCAP*4;
    u32* msums  = (u32*)(w + off); off += 64*4;
    u32* slist  = (u32*)(w + off); off += (size_t)NN*4;
    unsigned char* premat = (unsigned char*)(w + off); off += NE;
    u32* tkey   = (u32*)(w + off); off += (size_t)HCAP*4;
    u32* tmin   = (u32*)(w + off); off += (size_t)HCAP*4;
    u32* eslot  = (u32*)(w + off); off += (size_t)NE*4;

    ep_init<<<512, 256, 0, stream>>>(Wt, Ws, bt, bs, u, c0, counters,
                                     bt0, bt1, avail, cl, tkey, tmin, premat, mflag);
    ep_ynode<<<8192, 256, 0, stream>>>(x, u, y);
    ep_escore<<<1024, 256, 0, stream>>>(src, dst, rnd, y, c0, fkeyA, counters, out);

    // NFULL rounds of (rA, rB) with 2-buffer ping-pong bestT (key-only records)
    u64 *fk = fkeyA, *fk2 = fkeyB;
    u64 *bc = bt0, *bn = bt1;
    for (u32 rd = 0; rd < NFULL; rd++) {
        ep_rA<<<256, 256, 0, stream>>>(fk, src, dst, &counters[CNT0+rd], bc, avail);
        ep_rB<<<256, 256, 0, stream>>>(fk, src, dst, &counters[CNT0+rd], &counters[CNT0+rd+1],
                                       fk2, bc, bn, avail, mkeyA, premat, counters);
        u64* tp;
        tp = fk; fk = fk2; fk2 = tp;
        tp = bc; bc = bn; bn = tp;
    }

    ep_merge<<<SNB, 1024, 0, stream>>>(mkeyA, fk, counters, combK);
    // fused 6-pass sort (even # of passes -> sorted keys land back in combK)
    ms_sort<<<SNB, 64, 0, stream>>>(combK, combK2, hist, counters, &counters[32]);

    // walk over sorted list: tag-claim matching + fused msum
    ep_walk<<<1, 1024, 0, stream>>>(combK, src, dst, premat, counters, avail, mflag, msums);
    ep_memit<<<SNB, 1024, 0, stream>>>(combK, src, dst, mflag, msums, batch, Mlist, cl, out);

    ep_scanN<<<1, 1024, 0, stream>>>(cl, counters, slist, out);
    ep_out_nodes<<<128, 256, 0, stream>>>(cl, batch, counters, out);

    ep_newx_m<<<512, 256, 0, stream>>>(x, Wt, bt, Mlist, counters, out);
    ep_newx_s<<<1024, 256, 0, stream>>>(x, Wt, bt, slist, counters, out);

    ep_newei<<<1024, 256, 0, stream>>>(src, dst, cl, tkey, tmin, eslot, out);
    ep_valid<<<1024, 256, 0, stream>>>(tmin, eslot, out);
}

// Round 16
// 720.806 us; speedup vs baseline: 1.3043x; 1.0723x over previous
//
#include <hip/hip_runtime.h>
#include <stdint.h>

typedef unsigned int u32;
typedef unsigned long long u64;

#define NN 32768
#define NE 262144
#define NC 128

// output element offsets (ALL FLOAT32)
#define O0 0u               // new_x [NN*128]
#define O1 4194304u         // cluster [NN]
#define O2 4227072u         // new_batch [NN]
#define O3 4259840u         // new_edge_score [NN]
#define O4 4292608u         // num_clusters [1]
#define O5 4292609u         // new_ei [2*NE]
#define O6 4816897u         // edge_valid [NE]
#define O7 5079041u         // e [NE]

#define HCAP (1u<<19)
#define NFULL 8
#define CNT0 8
#define MCAP 16384
#define SCAP 32768
#define SNB 32
#define MAXK 0xFFFFFFFFFFFFFFFFull
#define EMASK 0x3FFFFu

// ---------------- init: prep (block 0) + all per-call state ----------------
__global__ void ep_init(const float* Wt, const float* Ws, const float* bt, const float* bs,
                        double* u, double* c0, u32* counters,
                        u64* b0, u64* b1, u32* avail, int* cl,
                        u32* tkey, u32* tmin, unsigned char* premat, u32* mflag) {
    u32 i = blockIdx.x*blockDim.x + threadIdx.x; // 512*256 = 131072
    if (blockIdx.x == 0 && threadIdx.x < 128) {
        int r = threadIdx.x;
        double s = 0.0;
        for (int j = 0; j < NC; j++) s += (double)Wt[r*NC+j] * (double)Ws[j];
        u[r] = s;
        if (r == 0) {
            double c = 0.0;
            for (int j = 0; j < NC; j++) c += (double)bt[j] * (double)Ws[j];
            *c0 = c + (double)bs[0];
        }
    }
    if (i < 64) counters[i] = 0u;
    if (i < NN) { b0[i] = MAXK; b1[i] = MAXK; cl[i] = -1; }
    if (i < NN/32) avail[i] = 0xFFFFFFFFu;
    if (i < SCAP) mflag[i] = 0u;
    ((unsigned short*)premat)[i] = 0;
    for (u32 j = i; j < HCAP; j += 131072u) { tkey[j] = 0xFFFFFFFFu; tmin[j] = 0xFFFFFFFFu; }
}

// ---------------- per-node f64 dot y[v] = x[v,:]·u ----------------
__global__ void ep_ynode(const float* x, const double* u, double* y) {
    int gid = blockIdx.x*blockDim.x + threadIdx.x;
    int v = gid >> 6, lane = threadIdx.x & 63;
    if (v >= NN) return;
    double t = (double)x[v*NC+lane]*u[lane] + (double)x[v*NC+lane+64]*u[lane+64];
    for (int off = 32; off; off >>= 1) t += __shfl_down(t, off, 64);
    if (lane == 0) y[v] = t;
}

// ---------------- per-edge score + unique priority + frontier push ----------------
__global__ void ep_escore(const int* src, const int* dst, const float* rnd, const double* y,
                          const double* c0, u64* fkey, u32* counters, float* out) {
    int e = blockIdx.x*blockDim.x + threadIdx.x;
    if (e >= NE) return;
    int s = src[e], d = dst[e];
    double z = y[s] + y[d] + *c0;
    double sc = 1.0/(1.0 + exp(-z));
    out[O7 + e] = (float)sc;
    u64 b = (u64)__double_as_longlong(z);
    u64 ord = (b & 0x8000000000000000ull) ? ~b : (b | 0x8000000000000000ull); // ascending z
    u64 P = ((~ord) & 0xFFFFFFFFFFFC0000ull) | (u64)(u32)e; // 46b score desc | 18b idx (unique)
    if ((double)rnd[e] <= sc) {
        u32 p = atomicAdd(&counters[CNT0], 1u);
        fkey[p] = P;
    }
}

// ---------------- full-grid priority-matching rounds (R6-exact, 2-buffer ping-pong) -
__device__ __forceinline__ bool ep_bit(const u32* a, u32 v) { return (a[v>>5] >> (v&31)) & 1u; }

__global__ void ep_rA(const u64* fkey, const int* src, const int* dst,
                      const u32* cnt, u64* bt, const u32* avail) {
    u32 n = *cnt;
    for (u32 i = blockIdx.x*blockDim.x + threadIdx.x; i < n; i += 65536u) {
        u64 P = fkey[i];
        u32 e = (u32)(P & EMASK);
        u32 s = (u32)src[e], d = (u32)dst[e];
        if (ep_bit(avail, s) && ep_bit(avail, d)) {
            atomicMin(&bt[s], P); atomicMin(&bt[d], P);
        }
    }
}

__global__ void ep_rB(const u64* fkey, const int* src, const int* dst,
                      const u32* cnt, u32* cntN, u64* fkeyN,
                      const u64* bt, u64* btN, u32* avail,
                      u64* mkey, unsigned char* premat, u32* counters) {
    u32 n = *cnt;
    for (u32 i = blockIdx.x*blockDim.x + threadIdx.x; i < n; i += 65536u) {
        u64 P = fkey[i];
        u32 e = (u32)(P & EMASK);
        u32 s = (u32)src[e], d = (u32)dst[e];
        if (!ep_bit(avail, s) || !ep_bit(avail, d)) continue; // dead
        if (bt[s] == P && bt[d] == P) {
            u32 slot = atomicAdd(&counters[2], 1u);
            mkey[slot] = P;
            premat[e] = 1;
            atomicAnd(&avail[s>>5], ~(1u<<(s&31)));
            atomicAnd(&avail[d>>5], ~(1u<<(d&31)));
        } else {
            u32 p = atomicAdd(cntN, 1u);
            fkeyN[p] = P;
            btN[s] = MAXK; btN[d] = MAXK;  // pre-reset next round's buffer
        }
    }
}

// ---------------- merge matched + remaining into one padded key list ----------------
__global__ void ep_merge(const u64* mk, const u64* fk, u32* counters, u64* ck) {
    u32 i = blockIdx.x*blockDim.x + threadIdx.x; // SNB*1024 threads
    u32 nm0 = counters[2];
    u32 cr  = counters[CNT0+NFULL];
    if (i == 0) { u32 tot = nm0 + cr; counters[4] = tot > SCAP ? SCAP : tot; }
    u64 K = MAXK;
    if (i < nm0) K = mk[i];
    else if (i < nm0 + cr && i < SCAP) K = fk[i-nm0];
    ck[i] = K;
}

// ---------------- radix sort: single-wave ballot hist / scan / ballot scatter -------
__device__ __forceinline__ u64 ep_peers(u32 d, bool real) {
    u64 m = ~0ull;
    #pragma unroll
    for (int b = 0; b < 8; b++) {
        u64 bb = __ballot((d >> b) & 1u);
        m &= ((d >> b) & 1u) ? bb : ~bb;
    }
    return m & __ballot(real);
}

__global__ void ms_hist(const u64* key, u32* hist, int shift, const u32* counters) {
    __shared__ u32 h[256];
    int t = threadIdx.x; // 64 threads = 1 wave, SNB blocks
    u32 total = counters[4];
    h[t] = 0; h[t+64] = 0; h[t+128] = 0; h[t+192] = 0;
    u32 blk = blockIdx.x;
    for (int j = 0; j < 16; j++) {
        u32 idx = blk*1024u + (u32)j*64u + (u32)t;
        bool real = idx < total;
        u64 k = real ? key[idx] : MAXK;
        u32 d = (u32)(k >> shift) & 255u;
        u64 m = ep_peers(d, real);
        if (real && t == (__ffsll((unsigned long long)m) - 1)) h[d] += (u32)__popcll(m);
    }
    hist[(u32)t*SNB + blk]       = h[t];
    hist[((u32)t+64)*SNB + blk]  = h[t+64];
    hist[((u32)t+128)*SNB + blk] = h[t+128];
    hist[((u32)t+192)*SNB + blk] = h[t+192];
}

__global__ void ms_scan(u32* hist) { // 8192 entries, 1 block x 256 threads
    __shared__ u32 w[4];
    int t = threadIdx.x;
    int base = t*32;
    u32 s = 0;
    for (int j = 0; j < 32; j++) s += hist[base+j];
    u32 x = s;
    for (int off = 1; off < 64; off <<= 1) { u32 yv = __shfl_up(x, off, 64); if ((t&63) >= off) x += yv; }
    if ((t&63) == 63) w[t>>6] = x;
    __syncthreads();
    if (t == 0) { u32 a = 0; for (int k = 0; k < 4; k++) { u32 tmp = w[k]; w[k] = a; a += tmp; } }
    __syncthreads();
    u32 run = w[t>>6] + x - s;
    for (int j = 0; j < 32; j++) { u32 tmp = hist[base+j]; hist[base+j] = run; run += tmp; }
}

__global__ void ms_scat(const u64* ki, u64* ko, const u32* hist, int shift, const u32* counters) {
    __shared__ u32 cnt[256];
    int t = threadIdx.x; // 64 threads = 1 wave, SNB blocks
    u32 total = counters[4];
    cnt[t] = 0; cnt[t+64] = 0; cnt[t+128] = 0; cnt[t+192] = 0;
    u32 blk = blockIdx.x;
    for (int j = 0; j < 16; j++) {
        u32 idx = blk*1024u + (u32)j*64u + (u32)t;
        bool real = idx < total;
        u64 k = real ? ki[idx] : MAXK;
        u32 d = (u32)(k >> shift) & 255u;
        u64 m = ep_peers(d, real);
        if (real) {
            u32 rank = (u32)__popcll(m & (((u64)1 << t) - 1ull));
            int leader = __ffsll((unsigned long long)m) - 1;
            u32 base = 0;
            if (t == leader) { base = cnt[d]; cnt[d] = base + (u32)__popcll(m); }
            base = __shfl(base, leader, 64);
            ko[hist[d*SNB + blk] + base + rank] = k;
        }
    }
}

// ---------------- barriered walk over sorted list (tag claims) + fused msum ---------
__global__ void __launch_bounds__(1024) ep_walk(const u64* sk, const int* src, const int* dst,
                                                const unsigned char* premat, u32* counters,
                                                const u32* availG, u32* mflag, u32* msums) {
    __shared__ u32 avail[1024];       // 32768 bits
    __shared__ u32 claim[16384];      // claim arbiter (node & 16383)
    __shared__ u32 part[1024];
    __shared__ u32 segs[32];
    int t = threadIdx.x;
    avail[t] = availG[t];
    for (int j = t; j < 16384; j += 1024) claim[j] = 0xFFFFFFFFu;
    __syncthreads();
    u32 total = counters[4];
    u32 iterTag = 0x3FFFFFu; // strictly decreasing across ALL iterations
    for (u32 base = 0; base < total; base += 1024) {
        u32 i = base + (u32)t;
        bool have = i < total;
        u32 s = 0, d = 0;
        int st = 1; // 0 candidate, 1 dead/pre, 2 matched
        if (have) {
            u32 e = (u32)(sk[i] & EMASK);
            if (premat[e]) {
                mflag[i] = 1u; // pre-matched: record, inert in claims
            } else {
                s = (u32)src[e]; d = (u32)dst[e];
                if (((avail[s>>5]>>(s&31))&1u) && ((avail[d>>5]>>(d&31))&1u)) st = 0;
            }
        }
        u32 hs = s & 16383u, hd = d & 16383u;
        for (int guard = 0; guard < 4096; guard++) {
            u32 tag = (iterTag << 10) | (u32)t;
            if (st == 0) { atomicMin(&claim[hs], tag); atomicMin(&claim[hd], tag); }
            __syncthreads();
            if (st == 0) {
                bool aok = ((avail[s>>5]>>(s&31))&1u) && ((avail[d>>5]>>(d&31))&1u);
                if (!aok) st = 1;
                else if (claim[hs] == tag && claim[hd] == tag) {
                    st = 2;
                    atomicAnd(&avail[s>>5], ~(1u<<(s&31)));
                    atomicAnd(&avail[d>>5], ~(1u<<(d&31)));
                    mflag[i] = 1u;
                }
            }
            iterTag--;
            if (__syncthreads_count(st == 0) == 0) break;
        }
    }
    __threadfence_block();
    __syncthreads();
    // fused msum + exclusive scan (32 segments of 1024 over mflag[32768])
    u32 p = 0; int b2 = t*32;
    for (int j = 0; j < 32; j++) p += mflag[b2+j];
    part[t] = p;
    __syncthreads();
    if (t < 32) { u32 sg = 0; for (int j = 0; j < 32; j++) sg += part[t*32+j]; segs[t] = sg; }
    __syncthreads();
    if (t == 0) { u32 a = 0; for (int g = 0; g < 32; g++) { msums[g] = a; a += segs[g]; } counters[2] = a; }
}

// ---------------- cid emit: parallel scan over match flags ----------------
__global__ void ep_memit(const u64* sk, const int* src, const int* dst,
                         const u32* mflag, const u32* msums,
                         const int* batch, u64* Mlist, int* cl, float* out) {
    __shared__ u32 w[16];
    int t = threadIdx.x;
    u32 i = blockIdx.x*1024 + t;
    u32 m = mflag[i];
    u32 x = m;
    for (int off = 1; off < 64; off <<= 1) { u32 y = __shfl_up(x, off, 64); if ((t&63) >= off) x += y; }
    if ((t&63) == 63) w[t>>6] = x;
    __syncthreads();
    if (t < 16) {
        u32 ww = w[t];
        for (int off = 1; off < 16; off <<= 1) { u32 y = __shfl_up(ww, off, 16); if (t >= off) ww += y; }
        w[t] = ww;
    }
    __syncthreads();
    u32 excl = ((t>>6) ? w[(t>>6)-1] : 0u) + x - m;
    if (m) {
        u32 cid = msums[blockIdx.x] + excl;
        u32 e = (u32)(sk[i] & EMASK);
        u32 s = (u32)src[e], d = (u32)dst[e];
        Mlist[cid] = ((u64)e << 30) | ((u64)s << 15) | (u64)d;
        cl[s] = (int)cid; cl[d] = (int)cid;
        u32 mx = s > d ? s : d; // last-writer-wins = max node index
        out[O2 + cid] = (float)batch[mx];
        out[O3 + cid] = out[O7 + e];
    }
}

// ---------------- singleton cid assignment + compacted singleton list ----------------
__global__ void ep_scanN(int* cl, u32* counters, u32* slist, float* out) {
    __shared__ u32 w[16];
    int t = threadIdx.x;
    int base = t*32;
    u32 s = 0;
    for (int j = 0; j < 32; j++) s += (cl[base+j] < 0) ? 1u : 0u;
    u32 x = s;
    for (int off = 1; off < 64; off <<= 1) { u32 y = __shfl_up(x, off, 64); if ((t&63) >= off) x += y; }
    if ((t&63) == 63) w[t>>6] = x;
    __syncthreads();
    if (t < 16) {
        u32 ww = w[t];
        for (int off = 1; off < 16; off <<= 1) { u32 y = __shfl_up(ww, off, 16); if (t >= off) ww += y; }
        w[t] = ww;
    }
    __syncthreads();
    u32 excl = ((t>>6) ? w[(t>>6)-1] : 0u) + x - s;
    u32 total = w[15];
    u32 nm = counters[2];
    if (t == 0) {
        counters[3] = nm + total;
        counters[6] = total;
        out[O4] = (float)(nm + total);
    }
    u32 run = nm + excl;
    for (int j = 0; j < 32; j++) {
        if (cl[base+j] < 0) {
            slist[run - nm] = (u32)(base + j);
            cl[base+j] = (int)(run++);
        }
    }
}

// ---------------- cluster ids + O2/O3 tails ----------------
__global__ void ep_out_nodes(const int* cl, const int* batch, const u32* counters, float* out) {
    int v = blockIdx.x*blockDim.x + threadIdx.x;
    if (v >= NN) return;
    u32 nm = counters[2], ncl = counters[3];
    int c = cl[v];
    out[O1 + v] = (float)c;
    if (c >= (int)nm) out[O2 + c] = (float)batch[v]; // singleton batch
    if (v >= (int)nm) out[O3 + v] = 1.0f;            // default edge score
    if (v >= (int)ncl) out[O2 + v] = 0.0f;           // batch tail zeros
}

// ---------------- new_x matched rows ----------------
__global__ void ep_newx_m(const float* x, const float* Wt, const float* bt,
                          const u64* Mlist, const u32* counters, float* out) {
    __shared__ u64 ml[32];
    __shared__ float m[32][128];
    u32 nm = counters[2];
    u32 base = blockIdx.x * 32u;
    if (base >= nm) return;
    int t = threadIdx.x, lane = t & 63, wv = t >> 6;
    if (t < 32) { u32 r = base + (u32)t; ml[t] = (r < nm) ? Mlist[r] : 0ull; }
    __syncthreads();
    for (int i = t; i < 4096; i += 256) {
        int r = i >> 7, k = i & 127;
        u64 v = ml[r];
        u32 s = (u32)((v>>15)&0x7FFF), d = (u32)(v&0x7FFF);
        m[r][k] = x[s*NC+k] + x[d*NC+k];
    }
    __syncthreads();
    float a0[8], a1[8];
    #pragma unroll
    for (int r = 0; r < 8; r++) { a0[r] = bt[lane]; a1[r] = bt[lane+64]; }
    for (int k = 0; k < 128; k++) {
        float w0 = Wt[k*NC+lane], w1 = Wt[k*NC+lane+64];
        #pragma unroll
        for (int r = 0; r < 8; r++) { float mm = m[wv*8+r][k]; a0[r] += mm*w0; a1[r] += mm*w1; }
    }
    #pragma unroll
    for (int r = 0; r < 8; r++) {
        u32 row = base + (u32)(wv*8 + r);
        if (row < nm) {
            out[O0 + (size_t)row*NC + lane]      = a0[r];
            out[O0 + (size_t)row*NC + lane + 64] = a1[r];
        }
    }
}

// ---------------- new_x singleton rows + zero tail ----------------
__global__ void ep_newx_s(const float* x, const float* Wt, const float* bt,
                          const u32* slist, const u32* counters, float* out) {
    __shared__ u32 nodes[32];
    __shared__ float m[32][128];
    u32 nm = counters[2], ncl = counters[3], sc = counters[6];
    u32 base = nm + blockIdx.x * 32u; // grid 1024 blocks covers rows [nm, nm+32768)
    if (base >= NN) return;
    int t = threadIdx.x, lane = t & 63, wv = t >> 6;
    if (base >= ncl) { // pure zero rows
        for (int i = t; i < 4096; i += 256) {
            u32 row = base + (u32)(i >> 7);
            if (row < NN) out[O0 + (size_t)row*NC + (i & 127)] = 0.0f;
        }
        return;
    }
    if (t < 32) { u32 p = base - nm + (u32)t; nodes[t] = (p < sc) ? slist[p] : slist[0]; }
    __syncthreads();
    for (int i = t; i < 4096; i += 256) {
        int r = i >> 7, k = i & 127;
        m[r][k] = 2.0f * x[nodes[r]*NC + k];
    }
    __syncthreads();
    float a0[8], a1[8];
    #pragma unroll
    for (int r = 0; r < 8; r++) { a0[r] = bt[lane]; a1[r] = bt[lane+64]; }
    for (int k = 0; k < 128; k++) {
        float w0 = Wt[k*NC+lane], w1 = Wt[k*NC+lane+64];
        #pragma unroll
        for (int r = 0; r < 8; r++) { float mm = m[wv*8+r][k]; a0[r] += mm*w0; a1[r] += mm*w1; }
    }
    #pragma unroll
    for (int r = 0; r < 8; r++) {
        u32 row = base + (u32)(wv*8 + r);
        if (row >= NN) continue;
        if (row < ncl) {
            out[O0 + (size_t)row*NC + lane]      = a0[r];
            out[O0 + (size_t)row*NC + lane + 64] = a1[r];
        } else {
            out[O0 + (size_t)row*NC + lane]      = 0.0f;
            out[O0 + (size_t)row*NC + lane + 64] = 0.0f;
        }
    }
}

// ---------------- new_ei + edge_valid via min-index hash ----------------
__global__ void ep_newei(const int* src, const int* dst, const int* cl,
                         u32* tkey, u32* tmin, u32* eslot, float* out) {
    int e = blockIdx.x*blockDim.x + threadIdx.x;
    if (e >= NE) return;
    u32 cs = (u32)cl[src[e]], cd = (u32)cl[dst[e]];
    out[O5 + e]      = (float)cs;
    out[O5 + NE + e] = (float)cd;
    u32 key = (cs << 15) | cd;
    u32 slot = ((key * 2654435761u) >> 11) & (HCAP-1);
    while (true) {
        u32 k = tkey[slot];
        if (k == key) break;
        if (k == 0xFFFFFFFFu) {
            u32 old = atomicCAS(&tkey[slot], 0xFFFFFFFFu, key);
            if (old == 0xFFFFFFFFu || old == key) break;
        }
        slot = (slot + 1) & (HCAP-1);
    }
    eslot[e] = slot | ((cs != cd) ? 0x80000000u : 0u);
    atomicMin(&tmin[slot], (u32)e);
}

__global__ void ep_valid(const u32* tmin, const u32* eslot, float* out) {
    int e = blockIdx.x*blockDim.x + threadIdx.x;
    if (e >= NE) return;
    u32 sl = eslot[e];
    bool valid = (tmin[sl & 0x7FFFFFFFu] == (u32)e) && (sl >> 31);
    out[O6 + e] = valid ? 1.0f : 0.0f;
}

// =============================== host ===============================
extern "C" void kernel_launch(void* const* d_in, const int* in_sizes, int n_in,
                              void* d_out, int out_size, void* d_ws, size_t ws_size,
                              hipStream_t stream) {
    (void)in_sizes; (void)n_in; (void)out_size; (void)ws_size;
    const float* x    = (const float*)d_in[0];
    const int*   ei   = (const int*)d_in[1];
    const int*   src  = ei;
    const int*   dst  = ei + NE;
    const int*   batch= (const int*)d_in[2];
    const float* rnd  = (const float*)d_in[3];
    const float* Wt   = (const float*)d_in[4];
    const float* bt   = (const float*)d_in[5];
    const float* Ws   = (const float*)d_in[6];
    const float* bs   = (const float*)d_in[7];
    float* out = (float*)d_out;

    char* w = (char*)d_ws;
    double* u  = (double*)w;
    double* c0 = (double*)(w + 1024);
    u32* counters = (u32*)(w + 2048);
    size_t off = 4096;
    double* y   = (double*)(w + off); off += (size_t)NN*8;
    u64* fkeyA  = (u64*)(w + off); off += (size_t)NE*8;
    u64* fkeyB  = (u64*)(w + off); off += (size_t)NE*8;
    u64* mkeyA  = (u64*)(w + off); off += (size_t)MCAP*8;
    u64* combK  = (u64*)(w + off); off += (size_t)SCAP*8;
    u64* combK2 = (u64*)(w + off); off += (size_t)SCAP*8;
    u64* bt0    = (u64*)(w + off); off += (size_t)NN*8;
    u64* bt1    = (u64*)(w + off); off += (size_t)NN*8;
    u32* avail  = (u32*)(w + off); off += NN/8;
    int* cl     = (int*)(w + off); off += (size_t)NN*4;
    u64* Mlist  = (u64*)(w + off); off += (size_t)NN*8;
    u32* hist   = (u32*)(w + off); off += 8192*4;
    u32* mflag  = (u32*)(w + off); off += (size_t)SCAP*4;
    u32* msums  = (u32*)(w + off); off += 64*4;
    u32* slist  = (u32*)(w + off); off += (size_t)NN*4;
    unsigned char* premat = (unsigned char*)(w + off); off += NE;
    u32* tkey   = (u32*)(w + off); off += (size_t)HCAP*4;
    u32* tmin   = (u32*)(w + off); off += (size_t)HCAP*4;
    u32* eslot  = (u32*)(w + off); off += (size_t)NE*4;

    ep_init<<<512, 256, 0, stream>>>(Wt, Ws, bt, bs, u, c0, counters,
                                     bt0, bt1, avail, cl, tkey, tmin, premat, mflag);
    ep_ynode<<<8192, 256, 0, stream>>>(x, u, y);
    ep_escore<<<1024, 256, 0, stream>>>(src, dst, rnd, y, c0, fkeyA, counters, out);

    // NFULL rounds of (rA, rB) with 2-buffer ping-pong bestT (key-only records)
    u64 *fk = fkeyA, *fk2 = fkeyB;
    u64 *bc = bt0, *bn = bt1;
    for (u32 rd = 0; rd < NFULL; rd++) {
        ep_rA<<<256, 256, 0, stream>>>(fk, src, dst, &counters[CNT0+rd], bc, avail);
        ep_rB<<<256, 256, 0, stream>>>(fk, src, dst, &counters[CNT0+rd], &counters[CNT0+rd+1],
                                       fk2, bc, bn, avail, mkeyA, premat, counters);
        u64* tp;
        tp = fk; fk = fk2; fk2 = tp;
        tp = bc; bc = bn; bn = tp;
    }

    ep_merge<<<SNB, 1024, 0, stream>>>(mkeyA, fk, counters, combK);
    // 6-pass key-only radix sort, separate kernels (R13-proven)
    u64 *ki = combK, *ko = combK2;
    for (int p = 0; p < 6; p++) {
        int shift = 16 + p*8;
        ms_hist<<<SNB, 64, 0, stream>>>(ki, hist, shift, counters);
        ms_scan<<<1, 256, 0, stream>>>(hist);
        ms_scat<<<SNB, 64, 0, stream>>>(ki, ko, hist, shift, counters);
        u64* tp = ki; ki = ko; ko = tp;
    }
    // 6 passes (even) -> sorted keys in combK (positions < counters[4] valid)

    // walk over sorted list: tag-claim matching + fused msum
    ep_walk<<<1, 1024, 0, stream>>>(combK, src, dst, premat, counters, avail, mflag, msums);
    ep_memit<<<SNB, 1024, 0, stream>>>(combK, src, dst, mflag, msums, batch, Mlist, cl, out);

    ep_scanN<<<1, 1024, 0, stream>>>(cl, counters, slist, out);
    ep_out_nodes<<<128, 256, 0, stream>>>(cl, batch, counters, out);

    ep_newx_m<<<512, 256, 0, stream>>>(x, Wt, bt, Mlist, counters, out);
    ep_newx_s<<<1024, 256, 0, stream>>>(x, Wt, bt, slist, counters, out);

    ep_newei<<<1024, 256, 0, stream>>>(src, dst, cl, tkey, tmin, eslot, out);
    ep_valid<<<1024, 256, 0, stream>>>(tmin, eslot, out);
}

// Round 17
// 695.808 us; speedup vs baseline: 1.3512x; 1.0359x over previous
//
#include <hip/hip_runtime.h>
#include <stdint.h>

typedef unsigned int u32;
typedef unsigned long long u64;

#define NN 32768
#define NE 262144
#define NC 128

// output element offsets (ALL FLOAT32)
#define O0 0u               // new_x [NN*128]
#define O1 4194304u         // cluster [NN]
#define O2 4227072u         // new_batch [NN]
#define O3 4259840u         // new_edge_score [NN]
#define O4 4292608u         // num_clusters [1]
#define O5 4292609u         // new_ei [2*NE]
#define O6 4816897u         // edge_valid [NE]
#define O7 5079041u         // e [NE]

#define HCAP (1u<<19)
#define NFULL 8
#define CNT0 8
#define MCAP 16384
#define SCAP 32768
#define SNB 32
#define MAXK 0xFFFFFFFFFFFFFFFFull
#define EMASK 0x3FFFFu

// ---------------- init: prep (block 0) + all per-call state ----------------
__global__ void ep_init(const float* Wt, const float* Ws, const float* bt, const float* bs,
                        double* u, double* c0, u32* counters,
                        u64* b0, u64* b1, u32* avail, int* cl,
                        u32* tkey, u32* tmin, unsigned char* premat) {
    u32 i = blockIdx.x*blockDim.x + threadIdx.x; // 512*256 = 131072
    if (blockIdx.x == 0 && threadIdx.x < 128) {
        int r = threadIdx.x;
        double s = 0.0;
        for (int j = 0; j < NC; j++) s += (double)Wt[r*NC+j] * (double)Ws[j];
        u[r] = s;
        if (r == 0) {
            double c = 0.0;
            for (int j = 0; j < NC; j++) c += (double)bt[j] * (double)Ws[j];
            *c0 = c + (double)bs[0];
        }
    }
    if (i < 64) counters[i] = 0u;
    if (i < NN) { b0[i] = MAXK; b1[i] = MAXK; cl[i] = -1; }
    if (i < NN/32) avail[i] = 0xFFFFFFFFu;
    ((unsigned short*)premat)[i] = 0;
    for (u32 j = i; j < HCAP; j += 131072u) { tkey[j] = 0xFFFFFFFFu; tmin[j] = 0xFFFFFFFFu; }
}

// ---------------- per-node f64 dot y[v] = x[v,:]·u ----------------
__global__ void ep_ynode(const float* x, const double* u, double* y) {
    int gid = blockIdx.x*blockDim.x + threadIdx.x;
    int v = gid >> 6, lane = threadIdx.x & 63;
    if (v >= NN) return;
    double t = (double)x[v*NC+lane]*u[lane] + (double)x[v*NC+lane+64]*u[lane+64];
    for (int off = 32; off; off >>= 1) t += __shfl_down(t, off, 64);
    if (lane == 0) y[v] = t;
}

// ---------------- per-edge score + unique priority + frontier push ----------------
__global__ void ep_escore(const int* src, const int* dst, const float* rnd, const double* y,
                          const double* c0, u64* fkey, u32* counters, float* out) {
    int e = blockIdx.x*blockDim.x + threadIdx.x;
    if (e >= NE) return;
    int s = src[e], d = dst[e];
    double z = y[s] + y[d] + *c0;
    double sc = 1.0/(1.0 + exp(-z));
    out[O7 + e] = (float)sc;
    u64 b = (u64)__double_as_longlong(z);
    u64 ord = (b & 0x8000000000000000ull) ? ~b : (b | 0x8000000000000000ull); // ascending z
    u64 P = ((~ord) & 0xFFFFFFFFFFFC0000ull) | (u64)(u32)e; // 46b score desc | 18b idx (unique)
    if ((double)rnd[e] <= sc) {
        u32 p = atomicAdd(&counters[CNT0], 1u);
        fkey[p] = P;
    }
}

// ---------------- full-grid priority-matching rounds (R6-exact, 2-buffer ping-pong) -
__device__ __forceinline__ bool ep_bit(const u32* a, u32 v) { return (a[v>>5] >> (v&31)) & 1u; }

__global__ void ep_rA(const u64* fkey, const int* src, const int* dst,
                      const u32* cnt, u64* bt, const u32* avail) {
    u32 n = *cnt;
    for (u32 i = blockIdx.x*blockDim.x + threadIdx.x; i < n; i += 65536u) {
        u64 P = fkey[i];
        u32 e = (u32)(P & EMASK);
        u32 s = (u32)src[e], d = (u32)dst[e];
        if (ep_bit(avail, s) && ep_bit(avail, d)) {
            atomicMin(&bt[s], P); atomicMin(&bt[d], P);
        }
    }
}

__global__ void ep_rB(const u64* fkey, const int* src, const int* dst,
                      const u32* cnt, u32* cntN, u64* fkeyN,
                      const u64* bt, u64* btN, u32* avail,
                      u64* mkey, unsigned char* premat, u32* counters) {
    u32 n = *cnt;
    for (u32 i = blockIdx.x*blockDim.x + threadIdx.x; i < n; i += 65536u) {
        u64 P = fkey[i];
        u32 e = (u32)(P & EMASK);
        u32 s = (u32)src[e], d = (u32)dst[e];
        if (!ep_bit(avail, s) || !ep_bit(avail, d)) continue; // dead
        if (bt[s] == P && bt[d] == P) {
            u32 slot = atomicAdd(&counters[2], 1u);
            mkey[slot] = P;
            premat[e] = 1;
            atomicAnd(&avail[s>>5], ~(1u<<(s&31)));
            atomicAnd(&avail[d>>5], ~(1u<<(d&31)));
        } else {
            u32 p = atomicAdd(cntN, 1u);
            fkeyN[p] = P;
            btN[s] = MAXK; btN[d] = MAXK;  // pre-reset next round's buffer
        }
    }
}

// ---------------- merge matched + remaining into one padded key list ----------------
__global__ void ep_merge(const u64* mk, const u64* fk, u32* counters, u64* ck) {
    u32 i = blockIdx.x*blockDim.x + threadIdx.x; // SNB*1024 threads
    u32 nm0 = counters[2];
    u32 cr  = counters[CNT0+NFULL];
    if (i == 0) { u32 tot = nm0 + cr; counters[4] = tot > SCAP ? SCAP : tot; }
    u64 K = MAXK;
    if (i < nm0) K = mk[i];
    else if (i < nm0 + cr && i < SCAP) K = fk[i-nm0];
    ck[i] = K;
}

// ---------------- radix sort: single-wave ballot hist / scan / ballot scatter -------
__device__ __forceinline__ u64 ep_peers(u32 d, bool real) {
    u64 m = ~0ull;
    #pragma unroll
    for (int b = 0; b < 8; b++) {
        u64 bb = __ballot((d >> b) & 1u);
        m &= ((d >> b) & 1u) ? bb : ~bb;
    }
    return m & __ballot(real);
}

__global__ void ms_hist(const u64* key, u32* hist, int shift, const u32* counters) {
    __shared__ u32 h[256];
    int t = threadIdx.x; // 64 threads = 1 wave, SNB blocks
    u32 total = counters[4];
    h[t] = 0; h[t+64] = 0; h[t+128] = 0; h[t+192] = 0;
    u32 blk = blockIdx.x;
    for (int j = 0; j < 16; j++) {
        u32 idx = blk*1024u + (u32)j*64u + (u32)t;
        bool real = idx < total;
        u64 k = real ? key[idx] : MAXK;
        u32 d = (u32)(k >> shift) & 255u;
        u64 m = ep_peers(d, real);
        if (real && t == (__ffsll((unsigned long long)m) - 1)) h[d] += (u32)__popcll(m);
    }
    hist[(u32)t*SNB + blk]       = h[t];
    hist[((u32)t+64)*SNB + blk]  = h[t+64];
    hist[((u32)t+128)*SNB + blk] = h[t+128];
    hist[((u32)t+192)*SNB + blk] = h[t+192];
}

__global__ void ms_scan(u32* hist) { // 8192 entries, 1 block x 256 threads
    __shared__ u32 w[4];
    int t = threadIdx.x;
    int base = t*32;
    u32 s = 0;
    for (int j = 0; j < 32; j++) s += hist[base+j];
    u32 x = s;
    for (int off = 1; off < 64; off <<= 1) { u32 yv = __shfl_up(x, off, 64); if ((t&63) >= off) x += yv; }
    if ((t&63) == 63) w[t>>6] = x;
    __syncthreads();
    if (t == 0) { u32 a = 0; for (int k = 0; k < 4; k++) { u32 tmp = w[k]; w[k] = a; a += tmp; } }
    __syncthreads();
    u32 run = w[t>>6] + x - s;
    for (int j = 0; j < 32; j++) { u32 tmp = hist[base+j]; hist[base+j] = run; run += tmp; }
}

__global__ void ms_scat(const u64* ki, u64* ko, const u32* hist, int shift, const u32* counters) {
    __shared__ u32 cnt[256];
    int t = threadIdx.x; // 64 threads = 1 wave, SNB blocks
    u32 total = counters[4];
    cnt[t] = 0; cnt[t+64] = 0; cnt[t+128] = 0; cnt[t+192] = 0;
    u32 blk = blockIdx.x;
    for (int j = 0; j < 16; j++) {
        u32 idx = blk*1024u + (u32)j*64u + (u32)t;
        bool real = idx < total;
        u64 k = real ? ki[idx] : MAXK;
        u32 d = (u32)(k >> shift) & 255u;
        u64 m = ep_peers(d, real);
        if (real) {
            u32 rank = (u32)__popcll(m & (((u64)1 << t) - 1ull));
            int leader = __ffsll((unsigned long long)m) - 1;
            u32 base = 0;
            if (t == leader) { base = cnt[d]; cnt[d] = base + (u32)__popcll(m); }
            base = __shfl(base, leader, 64);
            ko[hist[d*SNB + blk] + base + rank] = k;
        }
    }
}

// ---------------- candidate compaction over sorted key list (R13-proven) ------------
__global__ void ep_csum(const u64* sk, const unsigned char* premat, const u32* counters,
                        u32* mflag, u32* csums) {
    u32 i = blockIdx.x*1024 + threadIdx.x;
    u32 cnt = counters[4];
    bool pre = (i < cnt) && premat[(u32)(sk[i] & EMASK)];
    bool cand = (i < cnt) && !pre;
    mflag[i] = pre ? 1u : 0u;
    int c = __syncthreads_count(cand ? 1 : 0);
    if (threadIdx.x == 0) csums[blockIdx.x] = (u32)c;
}

__global__ void ep_cscan(u32* csums, u32* counters, int which) { // scans SNB values, 1 wave
    int t = threadIdx.x; // 64
    u32 v = (t < SNB) ? csums[t] : 0u;
    u32 x = v;
    for (int off = 1; off < 64; off <<= 1) { u32 y = __shfl_up(x, off, 64); if (t >= off) x += y; }
    if (t < SNB) csums[t] = x - v;
    if (t == SNB-1) counters[which] = x;
}

__global__ void ep_cemit(const u64* sk, const unsigned char* premat, const u32* counters,
                         const u32* csums, u32* candIdx) {
    __shared__ u32 w[16];
    int t = threadIdx.x;
    u32 i = blockIdx.x*1024 + t;
    u32 cnt = counters[4];
    bool pre = (i < cnt) && premat[(u32)(sk[i] & EMASK)];
    u32 c = ((i < cnt) && !pre) ? 1u : 0u;
    u32 x = c;
    for (int off = 1; off < 64; off <<= 1) { u32 y = __shfl_up(x, off, 64); if ((t&63) >= off) x += y; }
    if ((t&63) == 63) w[t>>6] = x;
    __syncthreads();
    if (t < 16) {
        u32 ww = w[t];
        for (int off = 1; off < 16; off <<= 1) { u32 y = __shfl_up(ww, off, 16); if (t >= off) ww += y; }
        w[t] = ww;
    }
    __syncthreads();
    u32 excl = ((t>>6) ? w[(t>>6)-1] : 0u) + x - c;
    if (c) candIdx[csums[blockIdx.x] + excl] = i;
}

// ---------------- barriered walk over candidates (tag claims) + fused msum ----------
__global__ void __launch_bounds__(1024) ep_walk(const u64* sk, const int* src, const int* dst,
                                                const u32* candIdx, u32* counters,
                                                const u32* availG, u32* mflag, u32* msums) {
    __shared__ u32 avail[1024];       // 32768 bits
    __shared__ u32 claim[16384];      // claim arbiter (node & 16383)
    __shared__ u32 part[1024];
    __shared__ u32 segs[32];
    int t = threadIdx.x;
    avail[t] = availG[t];
    for (int j = t; j < 16384; j += 1024) claim[j] = 0xFFFFFFFFu;
    __syncthreads();
    u32 ncand = counters[5];
    u32 iterTag = 0x3FFFFFu; // strictly decreasing across ALL iterations
    for (u32 base = 0; base < ncand; base += 1024) {
        u32 j = base + (u32)t;
        bool have = j < ncand;
        u32 i = 0, s = 0, d = 0;
        if (have) {
            i = candIdx[j];
            u32 e = (u32)(sk[i] & EMASK);
            s = (u32)src[e]; d = (u32)dst[e];
        }
        u32 hs = s & 16383u, hd = d & 16383u;
        int st = 1; // 0 candidate, 1 dead, 2 matched
        if (have && ((avail[s>>5]>>(s&31))&1u) && ((avail[d>>5]>>(d&31))&1u)) st = 0;
        for (int guard = 0; guard < 4096; guard++) {
            u32 tag = (iterTag << 10) | (u32)t;
            if (st == 0) { atomicMin(&claim[hs], tag); atomicMin(&claim[hd], tag); }
            __syncthreads();
            if (st == 0) {
                bool aok = ((avail[s>>5]>>(s&31))&1u) && ((avail[d>>5]>>(d&31))&1u);
                if (!aok) st = 1;
                else if (claim[hs] == tag && claim[hd] == tag) {
                    st = 2;
                    atomicAnd(&avail[s>>5], ~(1u<<(s&31)));
                    atomicAnd(&avail[d>>5], ~(1u<<(d&31)));
                    mflag[i] = 1u;
                }
            }
            iterTag--;
            if (__syncthreads_count(st == 0) == 0) break;
        }
    }
    __threadfence_block();
    __syncthreads();
    // fused msum + exclusive scan (32 segments of 1024 over mflag[32768])
    u32 p = 0; int b2 = t*32;
    for (int j = 0; j < 32; j++) p += mflag[b2+j];
    part[t] = p;
    __syncthreads();
    if (t < 32) { u32 sg = 0; for (int j = 0; j < 32; j++) sg += part[t*32+j]; segs[t] = sg; }
    __syncthreads();
    if (t == 0) { u32 a = 0; for (int g = 0; g < 32; g++) { msums[g] = a; a += segs[g]; } counters[2] = a; }
}

// ---------------- cid emit: parallel scan over match flags ----------------
__global__ void ep_memit(const u64* sk, const int* src, const int* dst,
                         const u32* mflag, const u32* msums,
                         const int* batch, u64* Mlist, int* cl, float* out) {
    __shared__ u32 w[16];
    int t = threadIdx.x;
    u32 i = blockIdx.x*1024 + t;
    u32 m = mflag[i];
    u32 x = m;
    for (int off = 1; off < 64; off <<= 1) { u32 y = __shfl_up(x, off, 64); if ((t&63) >= off) x += y; }
    if ((t&63) == 63) w[t>>6] = x;
    __syncthreads();
    if (t < 16) {
        u32 ww = w[t];
        for (int off = 1; off < 16; off <<= 1) { u32 y = __shfl_up(ww, off, 16); if (t >= off) ww += y; }
        w[t] = ww;
    }
    __syncthreads();
    u32 excl = ((t>>6) ? w[(t>>6)-1] : 0u) + x - m;
    if (m) {
        u32 cid = msums[blockIdx.x] + excl;
        u32 e = (u32)(sk[i] & EMASK);
        u32 s = (u32)src[e], d = (u32)dst[e];
        Mlist[cid] = ((u64)e << 30) | ((u64)s << 15) | (u64)d;
        cl[s] = (int)cid; cl[d] = (int)cid;
        u32 mx = s > d ? s : d; // last-writer-wins = max node index
        out[O2 + cid] = (float)batch[mx];
        out[O3 + cid] = out[O7 + e];
    }
}

// ---------------- singleton cid assignment + compacted singleton list ----------------
__global__ void ep_scanN(int* cl, u32* counters, u32* slist, float* out) {
    __shared__ u32 w[16];
    int t = threadIdx.x;
    int base = t*32;
    u32 s = 0;
    for (int j = 0; j < 32; j++) s += (cl[base+j] < 0) ? 1u : 0u;
    u32 x = s;
    for (int off = 1; off < 64; off <<= 1) { u32 y = __shfl_up(x, off, 64); if ((t&63) >= off) x += y; }
    if ((t&63) == 63) w[t>>6] = x;
    __syncthreads();
    if (t < 16) {
        u32 ww = w[t];
        for (int off = 1; off < 16; off <<= 1) { u32 y = __shfl_up(ww, off, 16); if (t >= off) ww += y; }
        w[t] = ww;
    }
    __syncthreads();
    u32 excl = ((t>>6) ? w[(t>>6)-1] : 0u) + x - s;
    u32 total = w[15];
    u32 nm = counters[2];
    if (t == 0) {
        counters[3] = nm + total;
        counters[6] = total;
        out[O4] = (float)(nm + total);
    }
    u32 run = nm + excl;
    for (int j = 0; j < 32; j++) {
        if (cl[base+j] < 0) {
            slist[run - nm] = (u32)(base + j);
            cl[base+j] = (int)(run++);
        }
    }
}

// ---------------- cluster ids + O2/O3 tails ----------------
__global__ void ep_out_nodes(const int* cl, const int* batch, const u32* counters, float* out) {
    int v = blockIdx.x*blockDim.x + threadIdx.x;
    if (v >= NN) return;
    u32 nm = counters[2], ncl = counters[3];
    int c = cl[v];
    out[O1 + v] = (float)c;
    if (c >= (int)nm) out[O2 + c] = (float)batch[v]; // singleton batch
    if (v >= (int)nm) out[O3 + v] = 1.0f;            // default edge score
    if (v >= (int)ncl) out[O2 + v] = 0.0f;           // batch tail zeros
}

// ---------------- new_x matched rows ----------------
__global__ void ep_newx_m(const float* x, const float* Wt, const float* bt,
                          const u64* Mlist, const u32* counters, float* out) {
    __shared__ u64 ml[32];
    __shared__ float m[32][128];
    u32 nm = counters[2];
    u32 base = blockIdx.x * 32u;
    if (base >= nm) return;
    int t = threadIdx.x, lane = t & 63, wv = t >> 6;
    if (t < 32) { u32 r = base + (u32)t; ml[t] = (r < nm) ? Mlist[r] : 0ull; }
    __syncthreads();
    for (int i = t; i < 4096; i += 256) {
        int r = i >> 7, k = i & 127;
        u64 v = ml[r];
        u32 s = (u32)((v>>15)&0x7FFF), d = (u32)(v&0x7FFF);
        m[r][k] = x[s*NC+k] + x[d*NC+k];
    }
    __syncthreads();
    float a0[8], a1[8];
    #pragma unroll
    for (int r = 0; r < 8; r++) { a0[r] = bt[lane]; a1[r] = bt[lane+64]; }
    for (int k = 0; k < 128; k++) {
        float w0 = Wt[k*NC+lane], w1 = Wt[k*NC+lane+64];
        #pragma unroll
        for (int r = 0; r < 8; r++) { float mm = m[wv*8+r][k]; a0[r] += mm*w0; a1[r] += mm*w1; }
    }
    #pragma unroll
    for (int r = 0; r < 8; r++) {
        u32 row = base + (u32)(wv*8 + r);
        if (row < nm) {
            out[O0 + (size_t)row*NC + lane]      = a0[r];
            out[O0 + (size_t)row*NC + lane + 64] = a1[r];
        }
    }
}

// ---------------- new_x singleton rows + zero tail ----------------
__global__ void ep_newx_s(const float* x, const float* Wt, const float* bt,
                          const u32* slist, const u32* counters, float* out) {
    __shared__ u32 nodes[32];
    __shared__ float m[32][128];
    u32 nm = counters[2], ncl = counters[3], sc = counters[6];
    u32 base = nm + blockIdx.x * 32u; // grid 1024 blocks covers rows [nm, nm+32768)
    if (base >= NN) return;
    int t = threadIdx.x, lane = t & 63, wv = t >> 6;
    if (base >= ncl) { // pure zero rows
        for (int i = t; i < 4096; i += 256) {
            u32 row = base + (u32)(i >> 7);
            if (row < NN) out[O0 + (size_t)row*NC + (i & 127)] = 0.0f;
        }
        return;
    }
    if (t < 32) { u32 p = base - nm + (u32)t; nodes[t] = (p < sc) ? slist[p] : slist[0]; }
    __syncthreads();
    for (int i = t; i < 4096; i += 256) {
        int r = i >> 7, k = i & 127;
        m[r][k] = 2.0f * x[nodes[r]*NC + k];
    }
    __syncthreads();
    float a0[8], a1[8];
    #pragma unroll
    for (int r = 0; r < 8; r++) { a0[r] = bt[lane]; a1[r] = bt[lane+64]; }
    for (int k = 0; k < 128; k++) {
        float w0 = Wt[k*NC+lane], w1 = Wt[k*NC+lane+64];
        #pragma unroll
        for (int r = 0; r < 8; r++) { float mm = m[wv*8+r][k]; a0[r] += mm*w0; a1[r] += mm*w1; }
    }
    #pragma unroll
    for (int r = 0; r < 8; r++) {
        u32 row = base + (u32)(wv*8 + r);
        if (row >= NN) continue;
        if (row < ncl) {
            out[O0 + (size_t)row*NC + lane]      = a0[r];
            out[O0 + (size_t)row*NC + lane + 64] = a1[r];
        } else {
            out[O0 + (size_t)row*NC + lane]      = 0.0f;
            out[O0 + (size_t)row*NC + lane + 64] = 0.0f;
        }
    }
}

// ---------------- new_ei + edge_valid via min-index hash ----------------
__global__ void ep_newei(const int* src, const int* dst, const int* cl,
                         u32* tkey, u32* tmin, u32* eslot, float* out) {
    int e = blockIdx.x*blockDim.x + threadIdx.x;
    if (e >= NE) return;
    u32 cs = (u32)cl[src[e]], cd = (u32)cl[dst[e]];
    out[O5 + e]      = (float)cs;
    out[O5 + NE + e] = (float)cd;
    u32 key = (cs << 15) | cd;
    u32 slot = ((key * 2654435761u) >> 11) & (HCAP-1);
    while (true) {
        u32 k = tkey[slot];
        if (k == key) break;
        if (k == 0xFFFFFFFFu) {
            u32 old = atomicCAS(&tkey[slot], 0xFFFFFFFFu, key);
            if (old == 0xFFFFFFFFu || old == key) break;
        }
        slot = (slot + 1) & (HCAP-1);
    }
    eslot[e] = slot | ((cs != cd) ? 0x80000000u : 0u);
    atomicMin(&tmin[slot], (u32)e);
}

__global__ void ep_valid(const u32* tmin, const u32* eslot, float* out) {
    int e = blockIdx.x*blockDim.x + threadIdx.x;
    if (e >= NE) return;
    u32 sl = eslot[e];
    bool valid = (tmin[sl & 0x7FFFFFFFu] == (u32)e) && (sl >> 31);
    out[O6 + e] = valid ? 1.0f : 0.0f;
}

// =============================== host ===============================
extern "C" void kernel_launch(void* const* d_in, const int* in_sizes, int n_in,
                              void* d_out, int out_size, void* d_ws, size_t ws_size,
                              hipStream_t stream) {
    (void)in_sizes; (void)n_in; (void)out_size; (void)ws_size;
    const float* x    = (const float*)d_in[0];
    const int*   ei   = (const int*)d_in[1];
    const int*   src  = ei;
    const int*   dst  = ei + NE;
    const int*   batch= (const int*)d_in[2];
    const float* rnd  = (const float*)d_in[3];
    const float* Wt   = (const float*)d_in[4];
    const float* bt   = (const float*)d_in[5];
    const float* Ws   = (const float*)d_in[6];
    const float* bs   = (const float*)d_in[7];
    float* out = (float*)d_out;

    char* w = (char*)d_ws;
    double* u  = (double*)w;
    double* c0 = (double*)(w + 1024);
    u32* counters = (u32*)(w + 2048);
    size_t off = 4096;
    double* y   = (double*)(w + off); off += (size_t)NN*8;
    u64* fkeyA  = (u64*)(w + off); off += (size_t)NE*8;
    u64* fkeyB  = (u64*)(w + off); off += (size_t)NE*8;
    u64* mkeyA  = (u64*)(w + off); off += (size_t)MCAP*8;
    u64* combK  = (u64*)(w + off); off += (size_t)SCAP*8;
    u64* combK2 = (u64*)(w + off); off += (size_t)SCAP*8;
    u64* bt0    = (u64*)(w + off); off += (size_t)NN*8;
    u64* bt1    = (u64*)(w + off); off += (size_t)NN*8;
    u32* avail  = (u32*)(w + off); off += NN/8;
    int* cl     = (int*)(w + off); off += (size_t)NN*4;
    u64* Mlist  = (u64*)(w + off); off += (size_t)NN*8;
    u32* hist   = (u32*)(w + off); off += 8192*4;
    u32* mflag  = (u32*)(w + off); off += (size_t)SCAP*4;
    u32* candIdx= (u32*)(w + off); off += (size_t)SCAP*4;
    u32* csums  = (u32*)(w + off); off += 64*4;
    u32* msums  = (u32*)(w + off); off += 64*4;
    u32* slist  = (u32*)(w + off); off += (size_t)NN*4;
    unsigned char* premat = (unsigned char*)(w + off); off += NE;
    u32* tkey   = (u32*)(w + off); off += (size_t)HCAP*4;
    u32* tmin   = (u32*)(w + off); off += (size_t)HCAP*4;
    u32* eslot  = (u32*)(w + off); off += (size_t)NE*4;

    ep_init<<<512, 256, 0, stream>>>(Wt, Ws, bt, bs, u, c0, counters,
                                     bt0, bt1, avail, cl, tkey, tmin, premat);
    ep_ynode<<<8192, 256, 0, stream>>>(x, u, y);
    ep_escore<<<1024, 256, 0, stream>>>(src, dst, rnd, y, c0, fkeyA, counters, out);

    // NFULL rounds of (rA, rB) with 2-buffer ping-pong bestT (key-only records)
    u64 *fk = fkeyA, *fk2 = fkeyB;
    u64 *bc = bt0, *bn = bt1;
    for (u32 rd = 0; rd < NFULL; rd++) {
        ep_rA<<<256, 256, 0, stream>>>(fk, src, dst, &counters[CNT0+rd], bc, avail);
        ep_rB<<<256, 256, 0, stream>>>(fk, src, dst, &counters[CNT0+rd], &counters[CNT0+rd+1],
                                       fk2, bc, bn, avail, mkeyA, premat, counters);
        u64* tp;
        tp = fk; fk = fk2; fk2 = tp;
        tp = bc; bc = bn; bn = tp;
    }

    ep_merge<<<SNB, 1024, 0, stream>>>(mkeyA, fk, counters, combK);
    // 6-pass key-only radix sort, separate kernels (R13-proven)
    u64 *ki = combK, *ko = combK2;
    for (int p = 0; p < 6; p++) {
        int shift = 16 + p*8;
        ms_hist<<<SNB, 64, 0, stream>>>(ki, hist, shift, counters);
        ms_scan<<<1, 256, 0, stream>>>(hist);
        ms_scat<<<SNB, 64, 0, stream>>>(ki, ko, hist, shift, counters);
        u64* tp = ki; ki = ko; ko = tp;
    }
    // 6 passes (even) -> sorted keys in combK (positions < counters[4] valid)

    // candidate compaction + walk over candIdx (tag claims) + fused msum
    ep_csum<<<SNB, 1024, 0, stream>>>(combK, premat, counters, mflag, csums);
    ep_cscan<<<1, 64, 0, stream>>>(csums, counters, 5);
    ep_cemit<<<SNB, 1024, 0, stream>>>(combK, premat, counters, csums, candIdx);
    ep_walk<<<1, 1024, 0, stream>>>(combK, src, dst, candIdx, counters, avail, mflag, msums);
    ep_memit<<<SNB, 1024, 0, stream>>>(combK, src, dst, mflag, msums, batch, Mlist, cl, out);

    ep_scanN<<<1, 1024, 0, stream>>>(cl, counters, slist, out);
    ep_out_nodes<<<128, 256, 0, stream>>>(cl, batch, counters, out);

    ep_newx_m<<<512, 256, 0, stream>>>(x, Wt, bt, Mlist, counters, out);
    ep_newx_s<<<1024, 256, 0, stream>>>(x, Wt, bt, slist, counters, out);

    ep_newei<<<1024, 256, 0, stream>>>(src, dst, cl, tkey, tmin, eslot, out);
    ep_valid<<<1024, 256, 0, stream>>>(tmin, eslot, out);
}